// Round 5
// baseline (1858.869 us; speedup 1.0000x reference)
//
#include <hip/hip_runtime.h>
#include <hip/hip_bf16.h>

#define NND 50000
#define NED 800000
#define NGR 64
#define EPSV 1e-5f

// ---------------- CSR build: histogram / scan / fill ----------------
__global__ void hist_kernel(const int* __restrict__ dst, int* __restrict__ cnt)
{
    int e = blockIdx.x * 256 + threadIdx.x;
    if (e < NED) atomicAdd(&cnt[dst[e]], 1);
}

__global__ void scan_kernel(const int* __restrict__ cnt, int* __restrict__ rowptr,
                            int* __restrict__ cursor)
{
    __shared__ int buf[1024];
    __shared__ int carry;
    int t = threadIdx.x;
    if (t == 0) carry = 0;
    __syncthreads();
    for (int base = 0; base < NND; base += 1024) {
        int v = (base + t < NND) ? cnt[base + t] : 0;
        buf[t] = v;
        __syncthreads();
        for (int off = 1; off < 1024; off <<= 1) {
            int x = (t >= off) ? buf[t - off] : 0;
            __syncthreads();
            buf[t] += x;
            __syncthreads();
        }
        int excl = buf[t] - v + carry;
        if (base + t < NND) { rowptr[base + t] = excl; cursor[base + t] = excl; }
        __syncthreads();
        if (t == 0) carry += buf[1023];
        __syncthreads();
    }
    if (t == 0) rowptr[NND] = carry;
}

__global__ void fill_kernel(const int* __restrict__ src, const int* __restrict__ dst,
                            const float* __restrict__ ew, int* __restrict__ cursor,
                            int* __restrict__ csrs, float* __restrict__ csrw)
{
    int e = blockIdx.x * 256 + threadIdx.x;
    if (e < NED) {
        int pos = atomicAdd(&cursor[dst[e]], 1);
        csrs[pos] = src[e];
        csrw[pos] = ew[e];
    }
}

// ---------------- K0: transpose node_feats [p][c] -> nfT [c][p] ----------------
__global__ void transpose_kernel(const float* __restrict__ nf, float* __restrict__ nfT)
{
    __shared__ float tile[32][33];
    int tx = threadIdx.x & 31, ty = threadIdx.x >> 5;   // 32 x 8
    int p0 = blockIdx.x * 32, c0 = blockIdx.y * 32;
#pragma unroll
    for (int i = 0; i < 4; i++) {
        int p = p0 + ty + i * 8;
        if (p < NND) tile[ty + i * 8][tx] = nf[(size_t)p * 128 + c0 + tx];
    }
    __syncthreads();
#pragma unroll
    for (int i = 0; i < 4; i++) {
        int c = c0 + ty + i * 8;
        int p = p0 + tx;
        if (p < NND) nfT[(size_t)c * NND + p] = tile[tx][ty + i * 8];
    }
}

// ---------------- K1: dilated conv1d, 3 branches (coalesced via nfT) ----------------
// X[br][p][96] = conv_b[br][o] + sum_{k,c} w[br][o][c][k] * nfT[c][p+(k-1)(br+1)]
__global__ void conv_kernel(const float* __restrict__ nfT, const float* __restrict__ cw,
                            const float* __restrict__ cb, float* __restrict__ X)
{
    __shared__ __align__(16) float wl[3 * 128 * 32];   // [k][c][j]
    const int t  = threadIdx.x;
    const int og = blockIdx.y;   // 0..2 (group of 32 out channels)
    const int br = blockIdx.z;   // 0..2
    for (int l = t; l < 3 * 128 * 32; l += 256) {
        int j = l & 31; int c = (l >> 5) & 127; int k = l >> 12;
        wl[l] = cw[(((size_t)br * 96 + og * 32 + j) * 128 + c) * 3 + k];
    }
    __syncthreads();
    int p = blockIdx.x * 256 + t;
    if (p >= NND) return;
    float acc[32];
#pragma unroll
    for (int j = 0; j < 32; j++) acc[j] = cb[br * 96 + og * 32 + j];
    const int d = br + 1;
    const bool okm = (p - d) >= 0;
    const bool okp = (p + d) < NND;
    for (int c = 0; c < 128; c++) {
        const float* col = nfT + (size_t)c * NND;
        float f0 = okm ? col[p - d] : 0.f;
        float f1 = col[p];
        float f2 = okp ? col[p + d] : 0.f;
        const float4* w0 = (const float4*)&wl[(0 * 128 + c) * 32];
        const float4* w1 = (const float4*)&wl[(1 * 128 + c) * 32];
        const float4* w2 = (const float4*)&wl[(2 * 128 + c) * 32];
#pragma unroll
        for (int jj = 0; jj < 8; jj++) {
            float4 a0 = w0[jj], a1 = w1[jj], a2 = w2[jj];
            acc[jj * 4 + 0] += f0 * a0.x + f1 * a1.x + f2 * a2.x;
            acc[jj * 4 + 1] += f0 * a0.y + f1 * a1.y + f2 * a2.y;
            acc[jj * 4 + 2] += f0 * a0.z + f1 * a1.z + f2 * a2.z;
            acc[jj * 4 + 3] += f0 * a0.w + f1 * a1.w + f2 * a2.w;
        }
    }
    float* xo = X + (size_t)br * NND * 96 + (size_t)p * 96 + og * 32;
#pragma unroll
    for (int j = 0; j < 32; j++) xo[j] = acc[j];
}

// ---------------- K2: Y = relu(X_i)+X_{i+1} + BN1 stats (register accum) ----------
__global__ void y_stats_kernel(const float* __restrict__ X, float* __restrict__ Y,
                               float* __restrict__ st1)
{
    __shared__ float ls[384], lq[384];
    int t = threadIdx.x;
    int br = blockIdx.y, ip1 = (br + 1) % 3;
    int c = t % 96, rsub = t / 96;
    const size_t NM = (size_t)NND * 96;
    int r0 = blockIdx.x * 64;
    int rend = r0 + 64 < NND ? r0 + 64 : NND;
    float s = 0.f, q = 0.f;
    const float* Xa = X + (size_t)br * NM;
    const float* Xb = X + (size_t)ip1 * NM;
    float* Yb = Y + (size_t)br * NM;
    for (int r = r0 + rsub; r < rend; r += 4) {
        size_t idx = (size_t)r * 96 + c;
        float a = Xa[idx]; a = a > 0.f ? a : 0.f;
        float y = a + Xb[idx];
        Yb[idx] = y;
        s += y; q += y * y;
    }
    ls[t] = s; lq[t] = q;
    __syncthreads();
    if (t < 96) {
        s = ls[t] + ls[t + 96] + ls[t + 192] + ls[t + 288];
        q = lq[t] + lq[t + 96] + lq[t + 192] + lq[t + 288];
        unsafeAtomicAdd(&st1[br * 96 + t], s);
        unsafeAtomicAdd(&st1[288 + br * 96 + t], q);
    }
}

// ---------------- BN finalize: scale/shift from (sum,sumsq) ----------------
__global__ void bn_finalize_kernel(const float* __restrict__ st, const float* __restrict__ g,
                                   const float* __restrict__ b,
                                   float* __restrict__ sc, float* __restrict__ sh,
                                   int C, int gmod)
{
    int t = threadIdx.x;
    if (t >= C) return;
    float mean = st[t] / (float)NND;
    float var  = st[C + t] / (float)NND - mean * mean;
    float rs = rsqrtf(var + EPSV);
    float gg = g[t % gmod], bb = b[t % gmod];
    float s = gg * rs;
    sc[t] = s; sh[t] = bb - mean * s;
}

// ---------------- K4: pull-based GCN aggregate with BN1 affine folded ----------
__global__ void pull_bn_kernel(const float* __restrict__ Y, const int* __restrict__ rowptr,
                               const int* __restrict__ csrs, const float* __restrict__ csrw,
                               const float* __restrict__ sc1, const float* __restrict__ sh1,
                               float* __restrict__ AGG)
{
    int id = blockIdx.x * 256 + threadIdx.x;
    if (id >= NND * 96) return;
    int br = blockIdx.y;
    int p = id / 96, c = id % 96;
    const size_t NM = (size_t)NND * 96;
    int beg = rowptr[p], end = rowptr[p + 1];
    float acc = 0.f, wsum = 0.f;
    const float* yb = Y + (size_t)br * NM;
    for (int i = beg; i < end; i++) {
        float w = csrw[i];
        acc += w * yb[(size_t)csrs[i] * 96 + c];
        wsum += w;
    }
    AGG[(size_t)br * NM + id] = sc1[br * 96 + c] * acc + sh1[br * 96 + c] * wsum;
}

// ---------------- pull-based gather (templated channel count) ----------------
template <int C>
__global__ void pull_kernel(const float* __restrict__ in, const int* __restrict__ rowptr,
                            const int* __restrict__ csrs, const float* __restrict__ csrw,
                            float* __restrict__ out)
{
    int id = blockIdx.x * 256 + threadIdx.x;
    if (id >= NND * C) return;
    int p = id / C, c = id % C;
    int beg = rowptr[p], end = rowptr[p + 1];
    float acc = 0.f;
    for (int i = beg; i < end; i++)
        acc += csrw[i] * in[(size_t)csrs[i] * C + c];
    out[id] = acc;
}

// ---------------- generic small matmul + bias + relu ----------------
__global__ void matmul_relu_kernel(const float* __restrict__ in, const float* __restrict__ W,
                                   const float* __restrict__ bias, float* __restrict__ out,
                                   int Cin, int Cout)
{
    int id = blockIdx.x * 256 + threadIdx.x;
    if (id >= NND * Cout) return;
    int p = id / Cout, o = id % Cout;
    float acc = bias[o];
    const float* row = in + (size_t)p * Cin;
    for (int c = 0; c < Cin; c++) acc += row[c] * W[c * Cout + o];
    out[id] = acc > 0.f ? acc : 0.f;
}

// ---------------- K6: press conv (3ch,K=3,SAME over 54) + BN2 stats ----------------
__global__ void press_stats_kernel(const float* __restrict__ H2, const float* __restrict__ pw,
                                   const float* __restrict__ pb, float* __restrict__ PRS,
                                   float* __restrict__ st2)
{
    __shared__ float ls[54], lq[54];
    int t = threadIdx.x;
    if (t < 54) { ls[t] = 0.f; lq[t] = 0.f; }
    __syncthreads();
    float pwf[9];
#pragma unroll
    for (int q = 0; q < 9; q++) pwf[q] = pw[q];
    float pbf = pb[0];
    const size_t NM = (size_t)NND * 54;
    size_t base = (size_t)blockIdx.x * 6912;
    for (int q = 0; q < 27; q++) {
        size_t idx = base + q * 256 + t;
        if (idx < NM) {
            int p = (int)(idx / 54), h = (int)(idx % 54);
            float sum = pbf;
#pragma unroll
            for (int i = 0; i < 3; i++)
#pragma unroll
                for (int k = 0; k < 3; k++) {
                    int hh = h + k - 1;
                    if (hh >= 0 && hh < 54)
                        sum += pwf[i * 3 + k] * H2[(size_t)i * NM + (size_t)p * 54 + hh];
                }
            PRS[idx] = sum;
            atomicAdd(&ls[h], sum); atomicAdd(&lq[h], sum * sum);
        }
    }
    __syncthreads();
    if (t < 54) {
        unsafeAtomicAdd(&st2[t], ls[t]);
        unsafeAtomicAdd(&st2[54 + t], lq[t]);
    }
}

// ---------------- K8: emd = affine(pressed); write fp32 out + keep fp32 ----------------
__global__ void emd_kernel(float* __restrict__ PRS, const float* __restrict__ sc2,
                           const float* __restrict__ sh2, float* __restrict__ outp)
{
    int id = blockIdx.x * 256 + threadIdx.x;
    if (id >= NND * 54) return;
    int h = id % 54;
    float v = PRS[id] * sc2[h] + sh2[h];
    PRS[id] = v;
    outp[id] = v;
}

// ---------------- K15: graph pooling of concat(h1,h2,h3) ----------------
__global__ void pool_kernel(const float* __restrict__ H1, const float* __restrict__ H2j,
                            const float* __restrict__ H3, const int* __restrict__ gid,
                            float* __restrict__ HG)
{
    int id = blockIdx.x * 256 + threadIdx.x;
    if (id >= NND * 75) return;
    int p = id / 75, c = id % 75;
    float v;
    if (c < 34)      v = H1[(size_t)p * 34 + c];
    else if (c < 59) v = H2j[(size_t)p * 25 + (c - 34)];
    else             v = H3[(size_t)p * 16 + (c - 59)];
    unsafeAtomicAdd(&HG[gid[p] * 75 + c], v);
}

// ---------------- K16: BN3 + cls matmuls, single block ----------------
__global__ void final_kernel(const float* __restrict__ HG, const float* __restrict__ g3,
                             const float* __restrict__ b3,
                             const float* __restrict__ w1, const float* __restrict__ b1,
                             const float* __restrict__ w2, const float* __restrict__ b2,
                             float* __restrict__ outp)
{
    __shared__ float hg[64 * 75];
    __shared__ float o1[64 * 120];
    __shared__ float sc[75], sh[75];
    int t = threadIdx.x;   // 512
    for (int idx = t; idx < 64 * 75; idx += 512) hg[idx] = HG[idx];
    __syncthreads();
    if (t < 75) {
        float s = 0.f, q = 0.f;
        for (int r = 0; r < 64; r++) { float v = hg[r * 75 + t]; s += v; q += v * v; }
        float m = s / 64.f, var = q / 64.f - m * m;
        float rs = rsqrtf(var + EPSV);
        float scale = g3[t] * rs;
        sc[t] = scale; sh[t] = b3[t] - m * scale;
    }
    __syncthreads();
    for (int idx = t; idx < 64 * 75; idx += 512) { int c = idx % 75; hg[idx] = hg[idx] * sc[c] + sh[c]; }
    __syncthreads();
    for (int idx = t; idx < 64 * 120; idx += 512) {
        int r = idx / 120, o = idx % 120;
        float a = b1[o];
        for (int c = 0; c < 75; c++) a += hg[r * 75 + c] * w1[c * 120 + o];
        o1[idx] = a;
    }
    __syncthreads();
    for (int idx = t; idx < 640; idx += 512) {
        int r = idx / 10, o = idx % 10;
        float a = b2[o];
        for (int k = 0; k < 120; k++) a += o1[r * 120 + k] * w2[k * 10 + o];
        outp[idx] = a;
    }
}

extern "C" void kernel_launch(void* const* d_in, const int* in_sizes, int n_in,
                              void* d_out, int out_size, void* d_ws, size_t ws_size,
                              hipStream_t stream)
{
    (void)in_sizes; (void)n_in; (void)out_size;
    const float* nf     = (const float*)d_in[0];
    const float* ew     = (const float*)d_in[1];
    const float* conv_w = (const float*)d_in[2];
    const float* conv_b = (const float*)d_in[3];
    const float* gcn_w  = (const float*)d_in[4];
    const float* gcn_b  = (const float*)d_in[5];
    const float* bn1_g = (const float*)d_in[6],  *bn1_b = (const float*)d_in[7];
    const float* bn2_g = (const float*)d_in[8],  *bn2_b = (const float*)d_in[9];
    const float* bn3_g = (const float*)d_in[10], *bn3_b = (const float*)d_in[11];
    const float* press_w = (const float*)d_in[12], *press_b = (const float*)d_in[13];
    const float* jk_w1 = (const float*)d_in[14], *jk_b1 = (const float*)d_in[15];
    const float* jk_w2 = (const float*)d_in[16], *jk_b2 = (const float*)d_in[17];
    const float* jk_w3 = (const float*)d_in[18], *jk_b3 = (const float*)d_in[19];
    const float* cls1_w = (const float*)d_in[20], *cls1_b = (const float*)d_in[21];
    const float* cls2_w = (const float*)d_in[22], *cls2_b = (const float*)d_in[23];
    const int* esrc = (const int*)d_in[24];
    const int* edst = (const int*)d_in[25];
    const int* gid  = (const int*)d_in[26];
    float* out = (float*)d_out;   // fp32 outputs: (logits[640], emd[2.7M])

    float* ws = (float*)d_ws;
    const size_t NM = (size_t)NND * 96;
    const size_t N54 = (size_t)NND * 54;
    float* X   = ws;                 // 3*NM   (aliased later: AGG)
    float* Y   = X + 3 * NM;         // 3*NM   (nfT during conv; jk buffers later)
    float* H2c = Y + 3 * NM;         // 3*N54
    float* PRS = H2c + 3 * N54;      // N54
    float* ST1 = PRS + N54;          // 576
    float* SC1 = ST1 + 576;          // 288
    float* SH1 = SC1 + 288;          // 288
    float* ST2 = SH1 + 288;          // 108
    float* SC2 = ST2 + 108;          // 54
    float* SH2 = SC2 + 54;           // 54
    float* HG  = SH2 + 54;           // 4800
    // CSR-by-dst scratch
    int* CNT    = (int*)(HG + 4800);     // 50000
    int* ROWPTR = CNT + NND;             // 50001
    int* CURSOR = ROWPTR + NND + 1;      // 50000
    int* CSRS   = CURSOR + NND;          // 800000
    float* CSRW = (float*)(CSRS + NED);  // 800000
    size_t need = (size_t)((float*)(CSRW + NED) - ws) * sizeof(float);
    if (ws_size < need) return;      // ws too small -> fail loudly in validation

    // aliases
    float* nfT  = Y;                 // [128][NND] — dead before y_stats writes Y
    float* AGG  = X;
    float* AGG1 = Y;                           // N*54
    float* H1j  = AGG1 + N54;                  // N*34
    float* AGG2 = H1j + (size_t)NND * 34;      // N*34
    float* H2j  = AGG2 + (size_t)NND * 34;     // N*25
    float* AGG3 = H2j + (size_t)NND * 25;      // N*25
    float* H3j  = AGG3 + (size_t)NND * 25;     // N*16

    // zero stats + HG (contiguous 6168 floats at ST1) and CSR histogram
    hipMemsetAsync(ST1, 0, 6168 * sizeof(float), stream);
    hipMemsetAsync(CNT, 0, NND * sizeof(int), stream);

    // CSR build (graph fixed per launch; reused by all 4 aggregation stages)
    hist_kernel<<<(NED + 255) / 256, 256, 0, stream>>>(edst, CNT);
    scan_kernel<<<1, 1024, 0, stream>>>(CNT, ROWPTR, CURSOR);
    fill_kernel<<<(NED + 255) / 256, 256, 0, stream>>>(esrc, edst, ew, CURSOR, CSRS, CSRW);

    // K0: transpose node feats into [c][p] (coalesced conv reads)
    transpose_kernel<<<dim3((NND + 31) / 32, 4), 256, 0, stream>>>(nf, nfT);

    // K1: dilated convs (coalesced)
    conv_kernel<<<dim3((NND + 255) / 256, 3, 3), 256, 0, stream>>>(nfT, conv_w, conv_b, X);

    // K2/K3: Y + BN1   (overwrites nfT region — conv already done)
    y_stats_kernel<<<dim3((NND + 63) / 64, 3), 384, 0, stream>>>(X, Y, ST1);
    bn_finalize_kernel<<<1, 512, 0, stream>>>(ST1, bn1_g, bn1_b, SC1, SH1, 288, 96);

    // K4: pull-based GCN aggregate (X region reused as AGG; no memset needed)
    pull_bn_kernel<<<dim3((NND * 96 + 255) / 256, 3), 256, 0, stream>>>(
        Y, ROWPTR, CSRS, CSRW, SC1, SH1, AGG);

    // K5: GCN matmul + relu per branch
    for (int i = 0; i < 3; i++)
        matmul_relu_kernel<<<(int)((N54 + 255) / 256), 256, 0, stream>>>(
            AGG + (size_t)i * NM, gcn_w + (size_t)i * 96 * 54, gcn_b + i * 54,
            H2c + (size_t)i * N54, 96, 54);

    // K6/K7/K8: press + BN2 + emd out (fp32 at element offset 640)
    press_stats_kernel<<<(int)((N54 + 6911) / 6912), 256, 0, stream>>>(H2c, press_w, press_b, PRS, ST2);
    bn_finalize_kernel<<<1, 512, 0, stream>>>(ST2, bn2_g, bn2_b, SC2, SH2, 54, 54);
    emd_kernel<<<(int)((N54 + 255) / 256), 256, 0, stream>>>(PRS, SC2, SH2, out + 640);

    // JK layer 1 (Y region dead -> jk buffers)
    pull_kernel<54><<<(NND * 54 + 255) / 256, 256, 0, stream>>>(PRS, ROWPTR, CSRS, CSRW, AGG1);
    matmul_relu_kernel<<<(NND * 34 + 255) / 256, 256, 0, stream>>>(AGG1, jk_w1, jk_b1, H1j, 54, 34);

    // JK layer 2
    pull_kernel<34><<<(NND * 34 + 255) / 256, 256, 0, stream>>>(H1j, ROWPTR, CSRS, CSRW, AGG2);
    matmul_relu_kernel<<<(NND * 25 + 255) / 256, 256, 0, stream>>>(AGG2, jk_w2, jk_b2, H2j, 34, 25);

    // JK layer 3
    pull_kernel<25><<<(NND * 25 + 255) / 256, 256, 0, stream>>>(H2j, ROWPTR, CSRS, CSRW, AGG3);
    matmul_relu_kernel<<<(NND * 16 + 255) / 256, 256, 0, stream>>>(AGG3, jk_w3, jk_b3, H3j, 25, 16);

    // pooling + final
    pool_kernel<<<(NND * 75 + 255) / 256, 256, 0, stream>>>(H1j, H2j, H3j, gid, HG);
    final_kernel<<<1, 512, 0, stream>>>(HG, bn3_g, bn3_b, cls1_w, cls1_b, cls2_w, cls2_b, out);
}

// Round 6
// 1435.170 us; speedup vs baseline: 1.2952x; 1.2952x over previous
//
#include <hip/hip_runtime.h>
#include <hip/hip_bf16.h>

#define NND 50000
#define NED 800000
#define NGR 64
#define EPSV 1e-5f

// ---------------- CSR build: histogram / 3-phase scan / fill ----------------
__global__ void hist_kernel(const int* __restrict__ dst, int* __restrict__ cnt)
{
    int e = blockIdx.x * 256 + threadIdx.x;
    if (e < NED) atomicAdd(&cnt[dst[e]], 1);
}

__global__ void scanA_kernel(const int* __restrict__ cnt, int* __restrict__ bsum)
{
    __shared__ int buf[256];
    int t = threadIdx.x, base = blockIdx.x * 1024;
    int s = 0;
    for (int i = t; i < 1024; i += 256) {
        int idx = base + i;
        s += (idx < NND) ? cnt[idx] : 0;
    }
    buf[t] = s; __syncthreads();
    for (int off = 128; off; off >>= 1) {
        if (t < off) buf[t] += buf[t + off];
        __syncthreads();
    }
    if (t == 0) bsum[blockIdx.x] = buf[0];
}

__global__ void scanB_kernel(int* __restrict__ bsum, int* __restrict__ rowptr, int nb)
{
    if (threadIdx.x == 0) {
        int acc = 0;
        for (int i = 0; i < nb; i++) { int v = bsum[i]; bsum[i] = acc; acc += v; }
        rowptr[NND] = acc;
    }
}

__global__ void scanC_kernel(const int* __restrict__ cnt, const int* __restrict__ bsum,
                             int* __restrict__ rowptr, int* __restrict__ cursor)
{
    __shared__ int buf[1024];
    int t = threadIdx.x, idx = blockIdx.x * 1024 + t;
    int v = (idx < NND) ? cnt[idx] : 0;
    buf[t] = v; __syncthreads();
    for (int off = 1; off < 1024; off <<= 1) {
        int x = (t >= off) ? buf[t - off] : 0;
        __syncthreads();
        buf[t] += x;
        __syncthreads();
    }
    if (idx < NND) {
        int excl = buf[t] - v + bsum[blockIdx.x];
        rowptr[idx] = excl; cursor[idx] = excl;
    }
}

__global__ void fill_kernel(const int* __restrict__ src, const int* __restrict__ dst,
                            const float* __restrict__ ew, int* __restrict__ cursor,
                            int* __restrict__ csrs, float* __restrict__ csrw)
{
    int e = blockIdx.x * 256 + threadIdx.x;
    if (e < NED) {
        int pos = atomicAdd(&cursor[dst[e]], 1);
        csrs[pos] = src[e];
        csrw[pos] = ew[e];
    }
}

// ---------------- graph ranges via binary search on sorted graph_ids ----------------
__global__ void grstart_kernel(const int* __restrict__ gid, int* __restrict__ gr)
{
    int t = threadIdx.x;
    if (t > NGR) return;
    if (t == NGR) { gr[NGR] = NND; return; }
    int lo = 0, hi = NND;
    while (lo < hi) { int mid = (lo + hi) >> 1; if (gid[mid] < t) lo = mid + 1; else hi = mid; }
    gr[t] = lo;
}

// ---------------- K0: transpose node_feats [p][c] -> nfT [c][p] ----------------
__global__ void transpose_kernel(const float* __restrict__ nf, float* __restrict__ nfT)
{
    __shared__ float tile[32][33];
    int tx = threadIdx.x & 31, ty = threadIdx.x >> 5;   // 32 x 8
    int p0 = blockIdx.x * 32, c0 = blockIdx.y * 32;
#pragma unroll
    for (int i = 0; i < 4; i++) {
        int p = p0 + ty + i * 8;
        if (p < NND) tile[ty + i * 8][tx] = nf[(size_t)p * 128 + c0 + tx];
    }
    __syncthreads();
#pragma unroll
    for (int i = 0; i < 4; i++) {
        int c = c0 + ty + i * 8;
        int p = p0 + tx;
        if (p < NND) nfT[(size_t)c * NND + p] = tile[tx][ty + i * 8];
    }
}

// ---------------- K1: dilated conv1d, 4 nodes/thread (LDS reads amortized) --------
__global__ __launch_bounds__(256)
void conv_kernel(const float* __restrict__ nfT, const float* __restrict__ cw,
                 const float* __restrict__ cb, float* __restrict__ X)
{
    __shared__ __align__(16) float wl[3 * 128 * 32];   // [k][c][j]
    const int t  = threadIdx.x;
    const int og = blockIdx.y;   // 0..2 (group of 32 out channels)
    const int br = blockIdx.z;   // 0..2
    for (int l = t; l < 3 * 128 * 32; l += 256) {
        int j = l & 31; int c = (l >> 5) & 127; int k = l >> 12;
        wl[l] = cw[(((size_t)br * 96 + og * 32 + j) * 128 + c) * 3 + k];
    }
    __syncthreads();
    const int pbase = blockIdx.x * 1024 + t;
    int pn[4]; bool ok[4], okm[4], okp[4];
    const int d = br + 1;
#pragma unroll
    for (int nn = 0; nn < 4; nn++) {
        pn[nn] = pbase + nn * 256;
        ok[nn] = pn[nn] < NND;
        okm[nn] = ok[nn] && (pn[nn] - d) >= 0;
        okp[nn] = ok[nn] && (pn[nn] + d) < NND;
    }
    float acc[4][32];
#pragma unroll
    for (int j = 0; j < 32; j++) {
        float b = cb[br * 96 + og * 32 + j];
#pragma unroll
        for (int nn = 0; nn < 4; nn++) acc[nn][j] = b;
    }
    for (int c = 0; c < 128; c++) {
        const float* col = nfT + (size_t)c * NND;
        float f0[4], f1[4], f2[4];
#pragma unroll
        for (int nn = 0; nn < 4; nn++) {
            f0[nn] = okm[nn] ? col[pn[nn] - d] : 0.f;
            f1[nn] = ok[nn]  ? col[pn[nn]]     : 0.f;
            f2[nn] = okp[nn] ? col[pn[nn] + d] : 0.f;
        }
        const float4* w0 = (const float4*)&wl[(0 * 128 + c) * 32];
        const float4* w1 = (const float4*)&wl[(1 * 128 + c) * 32];
        const float4* w2 = (const float4*)&wl[(2 * 128 + c) * 32];
#pragma unroll
        for (int jj = 0; jj < 8; jj++) {
            float4 a0 = w0[jj], a1 = w1[jj], a2 = w2[jj];
#pragma unroll
            for (int nn = 0; nn < 4; nn++) {
                acc[nn][jj * 4 + 0] += f0[nn] * a0.x + f1[nn] * a1.x + f2[nn] * a2.x;
                acc[nn][jj * 4 + 1] += f0[nn] * a0.y + f1[nn] * a1.y + f2[nn] * a2.y;
                acc[nn][jj * 4 + 2] += f0[nn] * a0.z + f1[nn] * a1.z + f2[nn] * a2.z;
                acc[nn][jj * 4 + 3] += f0[nn] * a0.w + f1[nn] * a1.w + f2[nn] * a2.w;
            }
        }
    }
#pragma unroll
    for (int nn = 0; nn < 4; nn++) {
        if (!ok[nn]) continue;
        float* xo = X + (size_t)br * NND * 96 + (size_t)pn[nn] * 96 + og * 32;
#pragma unroll
        for (int j = 0; j < 32; j++) xo[j] = acc[nn][j];
    }
}

// ---------------- K2: Y = relu(X_i)+X_{i+1} + BN1 stats (register accum) ----------
__global__ void y_stats_kernel(const float* __restrict__ X, float* __restrict__ Y,
                               float* __restrict__ st1)
{
    __shared__ float ls[384], lq[384];
    int t = threadIdx.x;
    int br = blockIdx.y, ip1 = (br + 1) % 3;
    int c = t % 96, rsub = t / 96;
    const size_t NM = (size_t)NND * 96;
    int r0 = blockIdx.x * 64;
    int rend = r0 + 64 < NND ? r0 + 64 : NND;
    float s = 0.f, q = 0.f;
    const float* Xa = X + (size_t)br * NM;
    const float* Xb = X + (size_t)ip1 * NM;
    float* Yb = Y + (size_t)br * NM;
    for (int r = r0 + rsub; r < rend; r += 4) {
        size_t idx = (size_t)r * 96 + c;
        float a = Xa[idx]; a = a > 0.f ? a : 0.f;
        float y = a + Xb[idx];
        Yb[idx] = y;
        s += y; q += y * y;
    }
    ls[t] = s; lq[t] = q;
    __syncthreads();
    if (t < 96) {
        s = ls[t] + ls[t + 96] + ls[t + 192] + ls[t + 288];
        q = lq[t] + lq[t + 96] + lq[t + 192] + lq[t + 288];
        unsafeAtomicAdd(&st1[br * 96 + t], s);
        unsafeAtomicAdd(&st1[288 + br * 96 + t], q);
    }
}

// ---------------- BN finalize ----------------
__global__ void bn_finalize_kernel(const float* __restrict__ st, const float* __restrict__ g,
                                   const float* __restrict__ b,
                                   float* __restrict__ sc, float* __restrict__ sh,
                                   int C, int gmod)
{
    int t = threadIdx.x;
    if (t >= C) return;
    float mean = st[t] / (float)NND;
    float var  = st[C + t] / (float)NND - mean * mean;
    float rs = rsqrtf(var + EPSV);
    float gg = g[t % gmod], bb = b[t % gmod];
    float s = gg * rs;
    sc[t] = s; sh[t] = bb - mean * s;
}

// ---------------- K4: pull GCN aggregate, 3 branches fused, float4 channels ------
// thread = (node p, channel-quad q of 24); BN1 affine folded
__global__ void pull_bn_kernel(const float* __restrict__ Y, const int* __restrict__ rowptr,
                               const int* __restrict__ csrs, const float* __restrict__ csrw,
                               const float* __restrict__ sc1, const float* __restrict__ sh1,
                               float* __restrict__ AGG)
{
    int id = blockIdx.x * 256 + threadIdx.x;
    if (id >= NND * 24) return;
    int p = id / 24, q = id % 24;
    const float4* Y4 = (const float4*)Y;
    const size_t NQ = (size_t)NND * 24;
    int beg = rowptr[p], end = rowptr[p + 1];
    float a0x=0,a0y=0,a0z=0,a0w=0, a1x=0,a1y=0,a1z=0,a1w=0, a2x=0,a2y=0,a2z=0,a2w=0;
    float wsum = 0.f;
    for (int i = beg; i < end; i++) {
        float w = csrw[i];
        size_t off = (size_t)csrs[i] * 24 + q;
        float4 v0 = Y4[off];
        float4 v1 = Y4[NQ + off];
        float4 v2 = Y4[2 * NQ + off];
        a0x += w * v0.x; a0y += w * v0.y; a0z += w * v0.z; a0w += w * v0.w;
        a1x += w * v1.x; a1y += w * v1.y; a1z += w * v1.z; a1w += w * v1.w;
        a2x += w * v2.x; a2y += w * v2.y; a2z += w * v2.z; a2w += w * v2.w;
        wsum += w;
    }
    const float4* S4 = (const float4*)sc1;
    const float4* H4 = (const float4*)sh1;
    float4* AG4 = (float4*)AGG;
    size_t ob = (size_t)p * 24 + q;
    {
        float4 s = S4[q], h = H4[q], r;
        r.x = s.x * a0x + h.x * wsum; r.y = s.y * a0y + h.y * wsum;
        r.z = s.z * a0z + h.z * wsum; r.w = s.w * a0w + h.w * wsum;
        AG4[ob] = r;
    }
    {
        float4 s = S4[24 + q], h = H4[24 + q], r;
        r.x = s.x * a1x + h.x * wsum; r.y = s.y * a1y + h.y * wsum;
        r.z = s.z * a1z + h.z * wsum; r.w = s.w * a1w + h.w * wsum;
        AG4[NQ + ob] = r;
    }
    {
        float4 s = S4[48 + q], h = H4[48 + q], r;
        r.x = s.x * a2x + h.x * wsum; r.y = s.y * a2y + h.y * wsum;
        r.z = s.z * a2z + h.z * wsum; r.w = s.w * a2w + h.w * wsum;
        AG4[2 * NQ + ob] = r;
    }
}

// ---------------- pull gather, float2-vectorized (C even) ----------------
template <int C>
__global__ void pull2_kernel(const float* __restrict__ in, const int* __restrict__ rowptr,
                             const int* __restrict__ csrs, const float* __restrict__ csrw,
                             float* __restrict__ out)
{
    constexpr int C2 = C / 2;
    int id = blockIdx.x * 256 + threadIdx.x;
    if (id >= NND * C2) return;
    int p = id / C2, q = id % C2;
    const float2* in2 = (const float2*)in;
    int beg = rowptr[p], end = rowptr[p + 1];
    float ax = 0.f, ay = 0.f;
    for (int i = beg; i < end; i++) {
        float w = csrw[i];
        float2 v = in2[(size_t)csrs[i] * C2 + q];
        ax += w * v.x; ay += w * v.y;
    }
    float2 r; r.x = ax; r.y = ay;
    ((float2*)out)[(size_t)p * C2 + q] = r;
}

// ---------------- pull gather, scalar (odd C) ----------------
template <int C>
__global__ void pull_kernel(const float* __restrict__ in, const int* __restrict__ rowptr,
                            const int* __restrict__ csrs, const float* __restrict__ csrw,
                            float* __restrict__ out)
{
    int id = blockIdx.x * 256 + threadIdx.x;
    if (id >= NND * C) return;
    int p = id / C, c = id % C;
    int beg = rowptr[p], end = rowptr[p + 1];
    float acc = 0.f;
    for (int i = beg; i < end; i++)
        acc += csrw[i] * in[(size_t)csrs[i] * C + c];
    out[id] = acc;
}

// ---------------- generic small matmul + bias + relu ----------------
__global__ void matmul_relu_kernel(const float* __restrict__ in, const float* __restrict__ W,
                                   const float* __restrict__ bias, float* __restrict__ out,
                                   int Cin, int Cout)
{
    int id = blockIdx.x * 256 + threadIdx.x;
    if (id >= NND * Cout) return;
    int p = id / Cout, o = id % Cout;
    float acc = bias[o];
    const float* row = in + (size_t)p * Cin;
    for (int c = 0; c < Cin; c++) acc += row[c] * W[c * Cout + o];
    out[id] = acc > 0.f ? acc : 0.f;
}

// ---------------- K6: press conv (3ch,K=3,SAME over 54) + BN2 stats ----------------
__global__ void press_stats_kernel(const float* __restrict__ H2, const float* __restrict__ pw,
                                   const float* __restrict__ pb, float* __restrict__ PRS,
                                   float* __restrict__ st2)
{
    __shared__ float ls[54], lq[54];
    int t = threadIdx.x;
    if (t < 54) { ls[t] = 0.f; lq[t] = 0.f; }
    __syncthreads();
    float pwf[9];
#pragma unroll
    for (int q = 0; q < 9; q++) pwf[q] = pw[q];
    float pbf = pb[0];
    const size_t NM = (size_t)NND * 54;
    size_t base = (size_t)blockIdx.x * 6912;
    for (int q = 0; q < 27; q++) {
        size_t idx = base + q * 256 + t;
        if (idx < NM) {
            int p = (int)(idx / 54), h = (int)(idx % 54);
            float sum = pbf;
#pragma unroll
            for (int i = 0; i < 3; i++)
#pragma unroll
                for (int k = 0; k < 3; k++) {
                    int hh = h + k - 1;
                    if (hh >= 0 && hh < 54)
                        sum += pwf[i * 3 + k] * H2[(size_t)i * NM + (size_t)p * 54 + hh];
                }
            PRS[idx] = sum;
            atomicAdd(&ls[h], sum); atomicAdd(&lq[h], sum * sum);
        }
    }
    __syncthreads();
    if (t < 54) {
        unsafeAtomicAdd(&st2[t], ls[t]);
        unsafeAtomicAdd(&st2[54 + t], lq[t]);
    }
}

// ---------------- K8: emd = affine(pressed) ----------------
__global__ void emd_kernel(float* __restrict__ PRS, const float* __restrict__ sc2,
                           const float* __restrict__ sh2, float* __restrict__ outp)
{
    int id = blockIdx.x * 256 + threadIdx.x;
    if (id >= NND * 54) return;
    int h = id % 54;
    float v = PRS[id] * sc2[h] + sh2[h];
    PRS[id] = v;
    outp[id] = v;
}

// ---------------- K15: graph pooling, block per graph, no atomics ----------------
__global__ void pool_kernel(const float* __restrict__ H1, const float* __restrict__ H2j,
                            const float* __restrict__ H3, const int* __restrict__ gr,
                            float* __restrict__ HG)
{
    __shared__ float part[4][75];
    int t = threadIdx.x;   // 300 = 75 x 4
    int c = t % 75, sub = t / 75;
    int g = blockIdx.x;
    int s = gr[g], e = gr[g + 1];
    float acc = 0.f;
    for (int p = s + sub; p < e; p += 4) {
        float v;
        if (c < 34)      v = H1[(size_t)p * 34 + c];
        else if (c < 59) v = H2j[(size_t)p * 25 + (c - 34)];
        else             v = H3[(size_t)p * 16 + (c - 59)];
        acc += v;
    }
    part[sub][c] = acc;
    __syncthreads();
    if (t < 75) HG[g * 75 + t] = part[0][t] + part[1][t] + part[2][t] + part[3][t];
}

// ---------------- K16: BN3 + cls matmuls, single block ----------------
__global__ void final_kernel(const float* __restrict__ HG, const float* __restrict__ g3,
                             const float* __restrict__ b3,
                             const float* __restrict__ w1, const float* __restrict__ b1,
                             const float* __restrict__ w2, const float* __restrict__ b2,
                             float* __restrict__ outp)
{
    __shared__ float hg[64 * 75];
    __shared__ float o1[64 * 120];
    __shared__ float sc[75], sh[75];
    int t = threadIdx.x;   // 512
    for (int idx = t; idx < 64 * 75; idx += 512) hg[idx] = HG[idx];
    __syncthreads();
    if (t < 75) {
        float s = 0.f, q = 0.f;
        for (int r = 0; r < 64; r++) { float v = hg[r * 75 + t]; s += v; q += v * v; }
        float m = s / 64.f, var = q / 64.f - m * m;
        float rs = rsqrtf(var + EPSV);
        float scale = g3[t] * rs;
        sc[t] = scale; sh[t] = b3[t] - m * scale;
    }
    __syncthreads();
    for (int idx = t; idx < 64 * 75; idx += 512) { int c = idx % 75; hg[idx] = hg[idx] * sc[c] + sh[c]; }
    __syncthreads();
    for (int idx = t; idx < 64 * 120; idx += 512) {
        int r = idx / 120, o = idx % 120;
        float a = b1[o];
        for (int c = 0; c < 75; c++) a += hg[r * 75 + c] * w1[c * 120 + o];
        o1[idx] = a;
    }
    __syncthreads();
    for (int idx = t; idx < 640; idx += 512) {
        int r = idx / 10, o = idx % 10;
        float a = b2[o];
        for (int k = 0; k < 120; k++) a += o1[r * 120 + k] * w2[k * 10 + o];
        outp[idx] = a;
    }
}

extern "C" void kernel_launch(void* const* d_in, const int* in_sizes, int n_in,
                              void* d_out, int out_size, void* d_ws, size_t ws_size,
                              hipStream_t stream)
{
    (void)in_sizes; (void)n_in; (void)out_size;
    const float* nf     = (const float*)d_in[0];
    const float* ew     = (const float*)d_in[1];
    const float* conv_w = (const float*)d_in[2];
    const float* conv_b = (const float*)d_in[3];
    const float* gcn_w  = (const float*)d_in[4];
    const float* gcn_b  = (const float*)d_in[5];
    const float* bn1_g = (const float*)d_in[6],  *bn1_b = (const float*)d_in[7];
    const float* bn2_g = (const float*)d_in[8],  *bn2_b = (const float*)d_in[9];
    const float* bn3_g = (const float*)d_in[10], *bn3_b = (const float*)d_in[11];
    const float* press_w = (const float*)d_in[12], *press_b = (const float*)d_in[13];
    const float* jk_w1 = (const float*)d_in[14], *jk_b1 = (const float*)d_in[15];
    const float* jk_w2 = (const float*)d_in[16], *jk_b2 = (const float*)d_in[17];
    const float* jk_w3 = (const float*)d_in[18], *jk_b3 = (const float*)d_in[19];
    const float* cls1_w = (const float*)d_in[20], *cls1_b = (const float*)d_in[21];
    const float* cls2_w = (const float*)d_in[22], *cls2_b = (const float*)d_in[23];
    const int* esrc = (const int*)d_in[24];
    const int* edst = (const int*)d_in[25];
    const int* gid  = (const int*)d_in[26];
    float* out = (float*)d_out;   // fp32 outputs: (logits[640], emd[2.7M])

    float* ws = (float*)d_ws;
    const size_t NM = (size_t)NND * 96;
    const size_t N54 = (size_t)NND * 54;
    float* X   = ws;                 // 3*NM   (aliased later: AGG)
    float* Y   = X + 3 * NM;         // 3*NM   (nfT during conv; jk buffers later)
    float* H2c = Y + 3 * NM;         // 3*N54
    float* PRS = H2c + 3 * N54;      // N54
    float* ST1 = PRS + N54;          // 576
    float* SC1 = ST1 + 576;          // 288
    float* SH1 = SC1 + 288;          // 288
    float* ST2 = SH1 + 288;          // 108
    float* SC2 = ST2 + 108;          // 54
    float* SH2 = SC2 + 54;           // 54
    float* HG  = SH2 + 54;           // 4800
    // CSR-by-dst + pooling scratch
    int* CNT    = (int*)(HG + 4800);     // 50000
    int* ROWPTR = CNT + NND;             // 50001
    int* CURSOR = ROWPTR + NND + 1;      // 50000
    int* CSRS   = CURSOR + NND;          // 800000
    float* CSRW = (float*)(CSRS + NED);  // 800000
    int* BSUM   = (int*)(CSRW + NED);    // 64 (49 used)
    int* GR     = BSUM + 64;             // 65
    size_t need = (size_t)((float*)(GR + 65) - ws) * sizeof(float);
    if (ws_size < need) return;      // ws too small -> fail loudly in validation

    // aliases
    float* nfT  = Y;                 // [128][NND] — dead before y_stats writes Y
    float* AGG  = X;
    float* AGG1 = Y;                           // N*54
    float* H1j  = AGG1 + N54;                  // N*34
    float* AGG2 = H1j + (size_t)NND * 34;      // N*34
    float* H2j  = AGG2 + (size_t)NND * 34;     // N*25
    float* AGG3 = H2j + (size_t)NND * 25;      // N*25
    float* H3j  = AGG3 + (size_t)NND * 25;     // N*16

    // zero stats (ST1..SH2 = 1368 floats) and CSR histogram
    hipMemsetAsync(ST1, 0, 1368 * sizeof(float), stream);
    hipMemsetAsync(CNT, 0, NND * sizeof(int), stream);

    // CSR build (multi-block scan) + graph ranges
    hist_kernel<<<(NED + 255) / 256, 256, 0, stream>>>(edst, CNT);
    scanA_kernel<<<49, 256, 0, stream>>>(CNT, BSUM);
    scanB_kernel<<<1, 64, 0, stream>>>(BSUM, ROWPTR, 49);
    scanC_kernel<<<49, 1024, 0, stream>>>(CNT, BSUM, ROWPTR, CURSOR);
    fill_kernel<<<(NED + 255) / 256, 256, 0, stream>>>(esrc, edst, ew, CURSOR, CSRS, CSRW);
    grstart_kernel<<<1, 128, 0, stream>>>(gid, GR);

    // K0: transpose node feats into [c][p] (coalesced conv reads)
    transpose_kernel<<<dim3((NND + 31) / 32, 4), 256, 0, stream>>>(nf, nfT);

    // K1: dilated convs (4 nodes/thread)
    conv_kernel<<<dim3((NND + 1023) / 1024, 3, 3), 256, 0, stream>>>(nfT, conv_w, conv_b, X);

    // K2/K3: Y + BN1   (overwrites nfT region — conv already done)
    y_stats_kernel<<<dim3((NND + 63) / 64, 3), 384, 0, stream>>>(X, Y, ST1);
    bn_finalize_kernel<<<1, 512, 0, stream>>>(ST1, bn1_g, bn1_b, SC1, SH1, 288, 96);

    // K4: pull GCN aggregate, 3 branches fused, float4 channels
    pull_bn_kernel<<<(NND * 24 + 255) / 256, 256, 0, stream>>>(
        Y, ROWPTR, CSRS, CSRW, SC1, SH1, AGG);

    // K5: GCN matmul + relu per branch
    for (int i = 0; i < 3; i++)
        matmul_relu_kernel<<<(int)((N54 + 255) / 256), 256, 0, stream>>>(
            AGG + (size_t)i * NM, gcn_w + (size_t)i * 96 * 54, gcn_b + i * 54,
            H2c + (size_t)i * N54, 96, 54);

    // K6/K7/K8: press + BN2 + emd out (fp32 at element offset 640)
    press_stats_kernel<<<(int)((N54 + 6911) / 6912), 256, 0, stream>>>(H2c, press_w, press_b, PRS, ST2);
    bn_finalize_kernel<<<1, 512, 0, stream>>>(ST2, bn2_g, bn2_b, SC2, SH2, 54, 54);
    emd_kernel<<<(int)((N54 + 255) / 256), 256, 0, stream>>>(PRS, SC2, SH2, out + 640);

    // JK layer 1 (Y region dead -> jk buffers)
    pull2_kernel<54><<<(NND * 27 + 255) / 256, 256, 0, stream>>>(PRS, ROWPTR, CSRS, CSRW, AGG1);
    matmul_relu_kernel<<<(NND * 34 + 255) / 256, 256, 0, stream>>>(AGG1, jk_w1, jk_b1, H1j, 54, 34);

    // JK layer 2
    pull2_kernel<34><<<(NND * 17 + 255) / 256, 256, 0, stream>>>(H1j, ROWPTR, CSRS, CSRW, AGG2);
    matmul_relu_kernel<<<(NND * 25 + 255) / 256, 256, 0, stream>>>(AGG2, jk_w2, jk_b2, H2j, 34, 25);

    // JK layer 3
    pull_kernel<25><<<(NND * 25 + 255) / 256, 256, 0, stream>>>(H2j, ROWPTR, CSRS, CSRW, AGG3);
    matmul_relu_kernel<<<(NND * 16 + 255) / 256, 256, 0, stream>>>(AGG3, jk_w3, jk_b3, H3j, 25, 16);

    // pooling (block per graph, no atomics) + final
    pool_kernel<<<NGR, 300, 0, stream>>>(H1j, H2j, H3j, GR, HG);
    final_kernel<<<1, 512, 0, stream>>>(HG, bn3_g, bn3_b, cls1_w, cls1_b, cls2_w, cls2_b, out);
}

// Round 7
// 1289.714 us; speedup vs baseline: 1.4413x; 1.1128x over previous
//
#include <hip/hip_runtime.h>
#include <hip/hip_bf16.h>

#define NND 50000
#define NED 800000
#define NGR 64
#define EPSV 1e-5f

// ---------------- CSR build: histogram / 3-phase scan / fill ----------------
__global__ void hist_kernel(const int* __restrict__ dst, int* __restrict__ cnt)
{
    int e = blockIdx.x * 256 + threadIdx.x;
    if (e < NED) atomicAdd(&cnt[dst[e]], 1);
}

__global__ void scanA_kernel(const int* __restrict__ cnt, int* __restrict__ bsum)
{
    __shared__ int buf[256];
    int t = threadIdx.x, base = blockIdx.x * 1024;
    int s = 0;
    for (int i = t; i < 1024; i += 256) {
        int idx = base + i;
        s += (idx < NND) ? cnt[idx] : 0;
    }
    buf[t] = s; __syncthreads();
    for (int off = 128; off; off >>= 1) {
        if (t < off) buf[t] += buf[t + off];
        __syncthreads();
    }
    if (t == 0) bsum[blockIdx.x] = buf[0];
}

__global__ void scanB_kernel(int* __restrict__ bsum, int* __restrict__ rowptr, int nb)
{
    if (threadIdx.x == 0) {
        int acc = 0;
        for (int i = 0; i < nb; i++) { int v = bsum[i]; bsum[i] = acc; acc += v; }
        rowptr[NND] = acc;
    }
}

__global__ void scanC_kernel(const int* __restrict__ cnt, const int* __restrict__ bsum,
                             int* __restrict__ rowptr, int* __restrict__ cursor)
{
    __shared__ int buf[1024];
    int t = threadIdx.x, idx = blockIdx.x * 1024 + t;
    int v = (idx < NND) ? cnt[idx] : 0;
    buf[t] = v; __syncthreads();
    for (int off = 1; off < 1024; off <<= 1) {
        int x = (t >= off) ? buf[t - off] : 0;
        __syncthreads();
        buf[t] += x;
        __syncthreads();
    }
    if (idx < NND) {
        int excl = buf[t] - v + bsum[blockIdx.x];
        rowptr[idx] = excl; cursor[idx] = excl;
    }
}

__global__ void fill_kernel(const int* __restrict__ src, const int* __restrict__ dst,
                            const float* __restrict__ ew, int* __restrict__ cursor,
                            int* __restrict__ csrs, float* __restrict__ csrw)
{
    int e = blockIdx.x * 256 + threadIdx.x;
    if (e < NED) {
        int pos = atomicAdd(&cursor[dst[e]], 1);
        csrs[pos] = src[e];
        csrw[pos] = ew[e];
    }
}

// ---------------- graph ranges via binary search on sorted graph_ids ----------------
__global__ void grstart_kernel(const int* __restrict__ gid, int* __restrict__ gr)
{
    int t = threadIdx.x;
    if (t > NGR) return;
    if (t == NGR) { gr[NGR] = NND; return; }
    int lo = 0, hi = NND;
    while (lo < hi) { int mid = (lo + hi) >> 1; if (gid[mid] < t) lo = mid + 1; else hi = mid; }
    gr[t] = lo;
}

// ---------------- K0: transpose node_feats [p][c] -> nfT [c][p] ----------------
__global__ void transpose_kernel(const float* __restrict__ nf, float* __restrict__ nfT)
{
    __shared__ float tile[32][33];
    int tx = threadIdx.x & 31, ty = threadIdx.x >> 5;   // 32 x 8
    int p0 = blockIdx.x * 32, c0 = blockIdx.y * 32;
#pragma unroll
    for (int i = 0; i < 4; i++) {
        int p = p0 + ty + i * 8;
        if (p < NND) tile[ty + i * 8][tx] = nf[(size_t)p * 128 + c0 + tx];
    }
    __syncthreads();
#pragma unroll
    for (int i = 0; i < 4; i++) {
        int c = c0 + ty + i * 8;
        int p = p0 + tx;
        if (p < NND) nfT[(size_t)c * NND + p] = tile[tx][ty + i * 8];
    }
}

// ---------------- K1: dilated conv1d, 2 nodes/thread (TLP vs LDS-amortization balance) --
__global__ __launch_bounds__(256)
void conv_kernel(const float* __restrict__ nfT, const float* __restrict__ cw,
                 const float* __restrict__ cb, float* __restrict__ X)
{
    __shared__ __align__(16) float wl[3 * 128 * 32];   // [k][c][j]
    const int t  = threadIdx.x;
    const int og = blockIdx.y;   // 0..2 (group of 32 out channels)
    const int br = blockIdx.z;   // 0..2
    for (int l = t; l < 3 * 128 * 32; l += 256) {
        int j = l & 31; int c = (l >> 5) & 127; int k = l >> 12;
        wl[l] = cw[(((size_t)br * 96 + og * 32 + j) * 128 + c) * 3 + k];
    }
    __syncthreads();
    const int pbase = blockIdx.x * 512 + t;
    int pn[2]; bool ok[2], okm[2], okp[2];
    const int d = br + 1;
#pragma unroll
    for (int nn = 0; nn < 2; nn++) {
        pn[nn] = pbase + nn * 256;
        ok[nn] = pn[nn] < NND;
        okm[nn] = ok[nn] && (pn[nn] - d) >= 0;
        okp[nn] = ok[nn] && (pn[nn] + d) < NND;
    }
    float acc[2][32];
#pragma unroll
    for (int j = 0; j < 32; j++) {
        float b = cb[br * 96 + og * 32 + j];
#pragma unroll
        for (int nn = 0; nn < 2; nn++) acc[nn][j] = b;
    }
    for (int c = 0; c < 128; c++) {
        const float* col = nfT + (size_t)c * NND;
        float f0[2], f1[2], f2[2];
#pragma unroll
        for (int nn = 0; nn < 2; nn++) {
            f0[nn] = okm[nn] ? col[pn[nn] - d] : 0.f;
            f1[nn] = ok[nn]  ? col[pn[nn]]     : 0.f;
            f2[nn] = okp[nn] ? col[pn[nn] + d] : 0.f;
        }
        const float4* w0 = (const float4*)&wl[(0 * 128 + c) * 32];
        const float4* w1 = (const float4*)&wl[(1 * 128 + c) * 32];
        const float4* w2 = (const float4*)&wl[(2 * 128 + c) * 32];
#pragma unroll
        for (int jj = 0; jj < 8; jj++) {
            float4 a0 = w0[jj], a1 = w1[jj], a2 = w2[jj];
#pragma unroll
            for (int nn = 0; nn < 2; nn++) {
                acc[nn][jj * 4 + 0] += f0[nn] * a0.x + f1[nn] * a1.x + f2[nn] * a2.x;
                acc[nn][jj * 4 + 1] += f0[nn] * a0.y + f1[nn] * a1.y + f2[nn] * a2.y;
                acc[nn][jj * 4 + 2] += f0[nn] * a0.z + f1[nn] * a1.z + f2[nn] * a2.z;
                acc[nn][jj * 4 + 3] += f0[nn] * a0.w + f1[nn] * a1.w + f2[nn] * a2.w;
            }
        }
    }
#pragma unroll
    for (int nn = 0; nn < 2; nn++) {
        if (!ok[nn]) continue;
        float* xo = X + (size_t)br * NND * 96 + (size_t)pn[nn] * 96 + og * 32;
#pragma unroll
        for (int j = 0; j < 32; j++) xo[j] = acc[nn][j];
    }
}

// ---------------- K2: Y = relu(X_i)+X_{i+1} + BN1 stats (register accum) ----------
__global__ void y_stats_kernel(const float* __restrict__ X, float* __restrict__ Y,
                               float* __restrict__ st1)
{
    __shared__ float ls[384], lq[384];
    int t = threadIdx.x;
    int br = blockIdx.y, ip1 = (br + 1) % 3;
    int c = t % 96, rsub = t / 96;
    const size_t NM = (size_t)NND * 96;
    int r0 = blockIdx.x * 64;
    int rend = r0 + 64 < NND ? r0 + 64 : NND;
    float s = 0.f, q = 0.f;
    const float* Xa = X + (size_t)br * NM;
    const float* Xb = X + (size_t)ip1 * NM;
    float* Yb = Y + (size_t)br * NM;
    for (int r = r0 + rsub; r < rend; r += 4) {
        size_t idx = (size_t)r * 96 + c;
        float a = Xa[idx]; a = a > 0.f ? a : 0.f;
        float y = a + Xb[idx];
        Yb[idx] = y;
        s += y; q += y * y;
    }
    ls[t] = s; lq[t] = q;
    __syncthreads();
    if (t < 96) {
        s = ls[t] + ls[t + 96] + ls[t + 192] + ls[t + 288];
        q = lq[t] + lq[t + 96] + lq[t + 192] + lq[t + 288];
        unsafeAtomicAdd(&st1[br * 96 + t], s);
        unsafeAtomicAdd(&st1[288 + br * 96 + t], q);
    }
}

// ---------------- BN finalize ----------------
__global__ void bn_finalize_kernel(const float* __restrict__ st, const float* __restrict__ g,
                                   const float* __restrict__ b,
                                   float* __restrict__ sc, float* __restrict__ sh,
                                   int C, int gmod)
{
    int t = threadIdx.x;
    if (t >= C) return;
    float mean = st[t] / (float)NND;
    float var  = st[C + t] / (float)NND - mean * mean;
    float rs = rsqrtf(var + EPSV);
    float gg = g[t % gmod], bb = b[t % gmod];
    float s = gg * rs;
    sc[t] = s; sh[t] = bb - mean * s;
}

// ---------------- K4: pull GCN aggregate, 3 branches fused, float4 channels ------
__global__ void pull_bn_kernel(const float* __restrict__ Y, const int* __restrict__ rowptr,
                               const int* __restrict__ csrs, const float* __restrict__ csrw,
                               const float* __restrict__ sc1, const float* __restrict__ sh1,
                               float* __restrict__ AGG)
{
    int id = blockIdx.x * 256 + threadIdx.x;
    if (id >= NND * 24) return;
    int p = id / 24, q = id % 24;
    const float4* Y4 = (const float4*)Y;
    const size_t NQ = (size_t)NND * 24;
    int beg = rowptr[p], end = rowptr[p + 1];
    float a0x=0,a0y=0,a0z=0,a0w=0, a1x=0,a1y=0,a1z=0,a1w=0, a2x=0,a2y=0,a2z=0,a2w=0;
    float wsum = 0.f;
    for (int i = beg; i < end; i++) {
        float w = csrw[i];
        size_t off = (size_t)csrs[i] * 24 + q;
        float4 v0 = Y4[off];
        float4 v1 = Y4[NQ + off];
        float4 v2 = Y4[2 * NQ + off];
        a0x += w * v0.x; a0y += w * v0.y; a0z += w * v0.z; a0w += w * v0.w;
        a1x += w * v1.x; a1y += w * v1.y; a1z += w * v1.z; a1w += w * v1.w;
        a2x += w * v2.x; a2y += w * v2.y; a2z += w * v2.z; a2w += w * v2.w;
        wsum += w;
    }
    const float4* S4 = (const float4*)sc1;
    const float4* H4 = (const float4*)sh1;
    float4* AG4 = (float4*)AGG;
    size_t ob = (size_t)p * 24 + q;
    {
        float4 s = S4[q], h = H4[q], r;
        r.x = s.x * a0x + h.x * wsum; r.y = s.y * a0y + h.y * wsum;
        r.z = s.z * a0z + h.z * wsum; r.w = s.w * a0w + h.w * wsum;
        AG4[ob] = r;
    }
    {
        float4 s = S4[24 + q], h = H4[24 + q], r;
        r.x = s.x * a1x + h.x * wsum; r.y = s.y * a1y + h.y * wsum;
        r.z = s.z * a1z + h.z * wsum; r.w = s.w * a1w + h.w * wsum;
        AG4[NQ + ob] = r;
    }
    {
        float4 s = S4[48 + q], h = H4[48 + q], r;
        r.x = s.x * a2x + h.x * wsum; r.y = s.y * a2y + h.y * wsum;
        r.z = s.z * a2z + h.z * wsum; r.w = s.w * a2w + h.w * wsum;
        AG4[2 * NQ + ob] = r;
    }
}

// ---------------- pull gather, float2-vectorized (C even) ----------------
template <int C>
__global__ void pull2_kernel(const float* __restrict__ in, const int* __restrict__ rowptr,
                             const int* __restrict__ csrs, const float* __restrict__ csrw,
                             float* __restrict__ out)
{
    constexpr int C2 = C / 2;
    int id = blockIdx.x * 256 + threadIdx.x;
    if (id >= NND * C2) return;
    int p = id / C2, q = id % C2;
    const float2* in2 = (const float2*)in;
    int beg = rowptr[p], end = rowptr[p + 1];
    float ax = 0.f, ay = 0.f;
    for (int i = beg; i < end; i++) {
        float w = csrw[i];
        float2 v = in2[(size_t)csrs[i] * C2 + q];
        ax += w * v.x; ay += w * v.y;
    }
    float2 r; r.x = ax; r.y = ay;
    ((float2*)out)[(size_t)p * C2 + q] = r;
}

// ---------------- pull gather, scalar (odd C) ----------------
template <int C>
__global__ void pull_kernel(const float* __restrict__ in, const int* __restrict__ rowptr,
                            const int* __restrict__ csrs, const float* __restrict__ csrw,
                            float* __restrict__ out)
{
    int id = blockIdx.x * 256 + threadIdx.x;
    if (id >= NND * C) return;
    int p = id / C, c = id % C;
    int beg = rowptr[p], end = rowptr[p + 1];
    float acc = 0.f;
    for (int i = beg; i < end; i++)
        acc += csrw[i] * in[(size_t)csrs[i] * C + c];
    out[id] = acc;
}

// ---------------- generic small matmul + bias + relu ----------------
__global__ void matmul_relu_kernel(const float* __restrict__ in, const float* __restrict__ W,
                                   const float* __restrict__ bias, float* __restrict__ out,
                                   int Cin, int Cout)
{
    int id = blockIdx.x * 256 + threadIdx.x;
    if (id >= NND * Cout) return;
    int p = id / Cout, o = id % Cout;
    float acc = bias[o];
    const float* row = in + (size_t)p * Cin;
    for (int c = 0; c < Cin; c++) acc += row[c] * W[c * Cout + o];
    out[id] = acc > 0.f ? acc : 0.f;
}

// ---------------- GCN matmul 96->54, 3 branches in one launch ----------------
__global__ void matmul3_relu_kernel(const float* __restrict__ AGG, const float* __restrict__ gw,
                                    const float* __restrict__ gb, float* __restrict__ H2c)
{
    int id = blockIdx.x * 256 + threadIdx.x;
    if (id >= NND * 54) return;
    int br = blockIdx.y;
    int p = id / 54, o = id % 54;
    const float* W = gw + (size_t)br * 96 * 54;
    float acc = gb[br * 54 + o];
    const float* row = AGG + (size_t)br * NND * 96 + (size_t)p * 96;
    for (int c = 0; c < 96; c++) acc += row[c] * W[c * 54 + o];
    H2c[(size_t)br * NND * 54 + id] = acc > 0.f ? acc : 0.f;
}

// ---------------- K6: press conv (3ch,K=3,SAME over 54) + BN2 stats ----------------
__global__ void press_stats_kernel(const float* __restrict__ H2, const float* __restrict__ pw,
                                   const float* __restrict__ pb, float* __restrict__ PRS,
                                   float* __restrict__ st2)
{
    __shared__ float ls[54], lq[54];
    int t = threadIdx.x;
    if (t < 54) { ls[t] = 0.f; lq[t] = 0.f; }
    __syncthreads();
    float pwf[9];
#pragma unroll
    for (int q = 0; q < 9; q++) pwf[q] = pw[q];
    float pbf = pb[0];
    const size_t NM = (size_t)NND * 54;
    size_t base = (size_t)blockIdx.x * 6912;
    for (int q = 0; q < 27; q++) {
        size_t idx = base + q * 256 + t;
        if (idx < NM) {
            int p = (int)(idx / 54), h = (int)(idx % 54);
            float sum = pbf;
#pragma unroll
            for (int i = 0; i < 3; i++)
#pragma unroll
                for (int k = 0; k < 3; k++) {
                    int hh = h + k - 1;
                    if (hh >= 0 && hh < 54)
                        sum += pwf[i * 3 + k] * H2[(size_t)i * NM + (size_t)p * 54 + hh];
                }
            PRS[idx] = sum;
            atomicAdd(&ls[h], sum); atomicAdd(&lq[h], sum * sum);
        }
    }
    __syncthreads();
    if (t < 54) {
        unsafeAtomicAdd(&st2[t], ls[t]);
        unsafeAtomicAdd(&st2[54 + t], lq[t]);
    }
}

// ---------------- K8: emd = affine(pressed) ----------------
__global__ void emd_kernel(float* __restrict__ PRS, const float* __restrict__ sc2,
                           const float* __restrict__ sh2, float* __restrict__ outp)
{
    int id = blockIdx.x * 256 + threadIdx.x;
    if (id >= NND * 54) return;
    int h = id % 54;
    float v = PRS[id] * sc2[h] + sh2[h];
    PRS[id] = v;
    outp[id] = v;
}

// ---------------- K15: graph pooling, block per graph, no atomics ----------------
__global__ void pool_kernel(const float* __restrict__ H1, const float* __restrict__ H2j,
                            const float* __restrict__ H3, const int* __restrict__ gr,
                            float* __restrict__ HG)
{
    __shared__ float part[4][75];
    int t = threadIdx.x;   // 300 = 75 x 4
    int c = t % 75, sub = t / 75;
    int g = blockIdx.x;
    int s = gr[g], e = gr[g + 1];
    float acc = 0.f;
    for (int p = s + sub; p < e; p += 4) {
        float v;
        if (c < 34)      v = H1[(size_t)p * 34 + c];
        else if (c < 59) v = H2j[(size_t)p * 25 + (c - 34)];
        else             v = H3[(size_t)p * 16 + (c - 59)];
        acc += v;
    }
    part[sub][c] = acc;
    __syncthreads();
    if (t < 75) HG[g * 75 + t] = part[0][t] + part[1][t] + part[2][t] + part[3][t];
}

// ---------------- K16: BN3 + cls matmuls, single block ----------------
__global__ void final_kernel(const float* __restrict__ HG, const float* __restrict__ g3,
                             const float* __restrict__ b3,
                             const float* __restrict__ w1, const float* __restrict__ b1,
                             const float* __restrict__ w2, const float* __restrict__ b2,
                             float* __restrict__ outp)
{
    __shared__ float hg[64 * 75];
    __shared__ float o1[64 * 120];
    __shared__ float sc[75], sh[75];
    int t = threadIdx.x;   // 512
    for (int idx = t; idx < 64 * 75; idx += 512) hg[idx] = HG[idx];
    __syncthreads();
    if (t < 75) {
        float s = 0.f, q = 0.f;
        for (int r = 0; r < 64; r++) { float v = hg[r * 75 + t]; s += v; q += v * v; }
        float m = s / 64.f, var = q / 64.f - m * m;
        float rs = rsqrtf(var + EPSV);
        float scale = g3[t] * rs;
        sc[t] = scale; sh[t] = b3[t] - m * scale;
    }
    __syncthreads();
    for (int idx = t; idx < 64 * 75; idx += 512) { int c = idx % 75; hg[idx] = hg[idx] * sc[c] + sh[c]; }
    __syncthreads();
    for (int idx = t; idx < 64 * 120; idx += 512) {
        int r = idx / 120, o = idx % 120;
        float a = b1[o];
        for (int c = 0; c < 75; c++) a += hg[r * 75 + c] * w1[c * 120 + o];
        o1[idx] = a;
    }
    __syncthreads();
    for (int idx = t; idx < 640; idx += 512) {
        int r = idx / 10, o = idx % 10;
        float a = b2[o];
        for (int k = 0; k < 120; k++) a += o1[r * 120 + k] * w2[k * 10 + o];
        outp[idx] = a;
    }
}

extern "C" void kernel_launch(void* const* d_in, const int* in_sizes, int n_in,
                              void* d_out, int out_size, void* d_ws, size_t ws_size,
                              hipStream_t stream)
{
    (void)in_sizes; (void)n_in; (void)out_size;
    const float* nf     = (const float*)d_in[0];
    const float* ew     = (const float*)d_in[1];
    const float* conv_w = (const float*)d_in[2];
    const float* conv_b = (const float*)d_in[3];
    const float* gcn_w  = (const float*)d_in[4];
    const float* gcn_b  = (const float*)d_in[5];
    const float* bn1_g = (const float*)d_in[6],  *bn1_b = (const float*)d_in[7];
    const float* bn2_g = (const float*)d_in[8],  *bn2_b = (const float*)d_in[9];
    const float* bn3_g = (const float*)d_in[10], *bn3_b = (const float*)d_in[11];
    const float* press_w = (const float*)d_in[12], *press_b = (const float*)d_in[13];
    const float* jk_w1 = (const float*)d_in[14], *jk_b1 = (const float*)d_in[15];
    const float* jk_w2 = (const float*)d_in[16], *jk_b2 = (const float*)d_in[17];
    const float* jk_w3 = (const float*)d_in[18], *jk_b3 = (const float*)d_in[19];
    const float* cls1_w = (const float*)d_in[20], *cls1_b = (const float*)d_in[21];
    const float* cls2_w = (const float*)d_in[22], *cls2_b = (const float*)d_in[23];
    const int* esrc = (const int*)d_in[24];
    const int* edst = (const int*)d_in[25];
    const int* gid  = (const int*)d_in[26];
    float* out = (float*)d_out;   // fp32 outputs: (logits[640], emd[2.7M])

    float* ws = (float*)d_ws;
    const size_t NM = (size_t)NND * 96;
    const size_t N54 = (size_t)NND * 54;
    float* X   = ws;                 // 3*NM   (aliased later: AGG)
    float* Y   = X + 3 * NM;         // 3*NM   (nfT during conv; jk buffers later)
    float* H2c = Y + 3 * NM;         // 3*N54
    float* PRS = H2c + 3 * N54;      // N54
    float* ST1 = PRS + N54;          // 576
    float* SC1 = ST1 + 576;          // 288
    float* SH1 = SC1 + 288;          // 288
    float* ST2 = SH1 + 288;          // 108
    float* SC2 = ST2 + 108;          // 54
    float* SH2 = SC2 + 54;           // 54
    float* HG  = SH2 + 54;           // 4800
    // CSR-by-dst + pooling scratch
    int* CNT    = (int*)(HG + 4800);     // 50000
    int* ROWPTR = CNT + NND;             // 50001
    int* CURSOR = ROWPTR + NND + 1;      // 50000
    int* CSRS   = CURSOR + NND;          // 800000
    float* CSRW = (float*)(CSRS + NED);  // 800000
    int* BSUM   = (int*)(CSRW + NED);    // 64 (49 used)
    int* GR     = BSUM + 64;             // 65
    size_t need = (size_t)((float*)(GR + 65) - ws) * sizeof(float);
    if (ws_size < need) return;      // ws too small -> fail loudly in validation

    // aliases
    float* nfT  = Y;                 // [128][NND] — dead before y_stats writes Y
    float* AGG  = X;
    float* AGG1 = Y;                           // N*54
    float* H1j  = AGG1 + N54;                  // N*34
    float* AGG2 = H1j + (size_t)NND * 34;      // N*34
    float* H2j  = AGG2 + (size_t)NND * 34;     // N*25
    float* AGG3 = H2j + (size_t)NND * 25;      // N*25
    float* H3j  = AGG3 + (size_t)NND * 25;     // N*16

    // zero stats (ST1..SH2 = 1368 floats) and CSR histogram
    hipMemsetAsync(ST1, 0, 1368 * sizeof(float), stream);
    hipMemsetAsync(CNT, 0, NND * sizeof(int), stream);

    // CSR build (multi-block scan) + graph ranges
    hist_kernel<<<(NED + 255) / 256, 256, 0, stream>>>(edst, CNT);
    scanA_kernel<<<49, 256, 0, stream>>>(CNT, BSUM);
    scanB_kernel<<<1, 64, 0, stream>>>(BSUM, ROWPTR, 49);
    scanC_kernel<<<49, 1024, 0, stream>>>(CNT, BSUM, ROWPTR, CURSOR);
    fill_kernel<<<(NED + 255) / 256, 256, 0, stream>>>(esrc, edst, ew, CURSOR, CSRS, CSRW);
    grstart_kernel<<<1, 128, 0, stream>>>(gid, GR);

    // K0: transpose node feats into [c][p] (coalesced conv reads)
    transpose_kernel<<<dim3((NND + 31) / 32, 4), 256, 0, stream>>>(nf, nfT);

    // K1: dilated convs (2 nodes/thread -> 882 blocks = 3.4 waves/SIMD)
    conv_kernel<<<dim3((NND + 511) / 512, 3, 3), 256, 0, stream>>>(nfT, conv_w, conv_b, X);

    // K2/K3: Y + BN1   (overwrites nfT region — conv already done)
    y_stats_kernel<<<dim3((NND + 63) / 64, 3), 384, 0, stream>>>(X, Y, ST1);
    bn_finalize_kernel<<<1, 512, 0, stream>>>(ST1, bn1_g, bn1_b, SC1, SH1, 288, 96);

    // K4: pull GCN aggregate, 3 branches fused, float4 channels
    pull_bn_kernel<<<(NND * 24 + 255) / 256, 256, 0, stream>>>(
        Y, ROWPTR, CSRS, CSRW, SC1, SH1, AGG);

    // K5: GCN matmul + relu, all 3 branches in one launch
    matmul3_relu_kernel<<<dim3((int)((N54 + 255) / 256), 3), 256, 0, stream>>>(
        AGG, gcn_w, gcn_b, H2c);

    // K6/K7/K8: press + BN2 + emd out (fp32 at element offset 640)
    press_stats_kernel<<<(int)((N54 + 6911) / 6912), 256, 0, stream>>>(H2c, press_w, press_b, PRS, ST2);
    bn_finalize_kernel<<<1, 512, 0, stream>>>(ST2, bn2_g, bn2_b, SC2, SH2, 54, 54);
    emd_kernel<<<(int)((N54 + 255) / 256), 256, 0, stream>>>(PRS, SC2, SH2, out + 640);

    // JK layer 1 (Y region dead -> jk buffers)
    pull2_kernel<54><<<(NND * 27 + 255) / 256, 256, 0, stream>>>(PRS, ROWPTR, CSRS, CSRW, AGG1);
    matmul_relu_kernel<<<(NND * 34 + 255) / 256, 256, 0, stream>>>(AGG1, jk_w1, jk_b1, H1j, 54, 34);

    // JK layer 2
    pull2_kernel<34><<<(NND * 17 + 255) / 256, 256, 0, stream>>>(H1j, ROWPTR, CSRS, CSRW, AGG2);
    matmul_relu_kernel<<<(NND * 25 + 255) / 256, 256, 0, stream>>>(AGG2, jk_w2, jk_b2, H2j, 34, 25);

    // JK layer 3
    pull_kernel<25><<<(NND * 25 + 255) / 256, 256, 0, stream>>>(H2j, ROWPTR, CSRS, CSRW, AGG3);
    matmul_relu_kernel<<<(NND * 16 + 255) / 256, 256, 0, stream>>>(AGG3, jk_w3, jk_b3, H3j, 25, 16);

    // pooling (block per graph, no atomics) + final
    pool_kernel<<<NGR, 300, 0, stream>>>(H1j, H2j, H3j, GR, HG);
    final_kernel<<<1, 512, 0, stream>>>(HG, bn3_g, bn3_b, cls1_w, cls1_b, cls2_w, cls2_b, out);
}

// Round 8
// 1244.466 us; speedup vs baseline: 1.4937x; 1.0364x over previous
//
#include <hip/hip_runtime.h>
#include <hip/hip_bf16.h>

#define NND 50000
#define NED 800000
#define NGR 64
#define EPSV 1e-5f
#define NSTR (NND + 8)   // padded column stride for nfT (4-elem zero guards)

// ---------------- CSR build: histogram / 3-phase scan / fill ----------------
__global__ void hist_kernel(const int* __restrict__ dst, int* __restrict__ cnt)
{
    int e = blockIdx.x * 256 + threadIdx.x;
    if (e < NED) atomicAdd(&cnt[dst[e]], 1);
}

__global__ void scanA_kernel(const int* __restrict__ cnt, int* __restrict__ bsum)
{
    __shared__ int buf[256];
    int t = threadIdx.x, base = blockIdx.x * 1024;
    int s = 0;
    for (int i = t; i < 1024; i += 256) {
        int idx = base + i;
        s += (idx < NND) ? cnt[idx] : 0;
    }
    buf[t] = s; __syncthreads();
    for (int off = 128; off; off >>= 1) {
        if (t < off) buf[t] += buf[t + off];
        __syncthreads();
    }
    if (t == 0) bsum[blockIdx.x] = buf[0];
}

__global__ void scanB_kernel(int* __restrict__ bsum, int* __restrict__ rowptr, int nb)
{
    if (threadIdx.x == 0) {
        int acc = 0;
        for (int i = 0; i < nb; i++) { int v = bsum[i]; bsum[i] = acc; acc += v; }
        rowptr[NND] = acc;
    }
}

__global__ void scanC_kernel(const int* __restrict__ cnt, const int* __restrict__ bsum,
                             int* __restrict__ rowptr, int* __restrict__ cursor)
{
    __shared__ int buf[1024];
    int t = threadIdx.x, idx = blockIdx.x * 1024 + t;
    int v = (idx < NND) ? cnt[idx] : 0;
    buf[t] = v; __syncthreads();
    for (int off = 1; off < 1024; off <<= 1) {
        int x = (t >= off) ? buf[t - off] : 0;
        __syncthreads();
        buf[t] += x;
        __syncthreads();
    }
    if (idx < NND) {
        int excl = buf[t] - v + bsum[blockIdx.x];
        rowptr[idx] = excl; cursor[idx] = excl;
    }
}

__global__ void fill_kernel(const int* __restrict__ src, const int* __restrict__ dst,
                            const float* __restrict__ ew, int* __restrict__ cursor,
                            int* __restrict__ csrs, float* __restrict__ csrw)
{
    int e = blockIdx.x * 256 + threadIdx.x;
    if (e < NED) {
        int pos = atomicAdd(&cursor[dst[e]], 1);
        csrs[pos] = src[e];
        csrw[pos] = ew[e];
    }
}

// ---------------- graph ranges via binary search on sorted graph_ids ----------------
__global__ void grstart_kernel(const int* __restrict__ gid, int* __restrict__ gr)
{
    int t = threadIdx.x;
    if (t > NGR) return;
    if (t == NGR) { gr[NGR] = NND; return; }
    int lo = 0, hi = NND;
    while (lo < hi) { int mid = (lo + hi) >> 1; if (gid[mid] < t) lo = mid + 1; else hi = mid; }
    gr[t] = lo;
}

// ---------------- K0: transpose node_feats [p][c] -> nfT [c][4+p] (padded) ---------
__global__ void transpose_kernel(const float* __restrict__ nf, float* __restrict__ nfT)
{
    __shared__ float tile[32][33];
    int tx = threadIdx.x & 31, ty = threadIdx.x >> 5;   // 32 x 8
    int p0 = blockIdx.x * 32, c0 = blockIdx.y * 32;
#pragma unroll
    for (int i = 0; i < 4; i++) {
        int p = p0 + ty + i * 8;
        if (p < NND) tile[ty + i * 8][tx] = nf[(size_t)p * 128 + c0 + tx];
    }
    __syncthreads();
#pragma unroll
    for (int i = 0; i < 4; i++) {
        int c = c0 + ty + i * 8;
        int p = p0 + tx;
        if (p < NND) nfT[(size_t)c * NSTR + 4 + p] = tile[tx][ty + i * 8];
    }
}

// zero the 4-elem guard bands of each padded column
__global__ void pad_kernel(float* __restrict__ nfT)
{
    int t = threadIdx.x;           // 1024 = 128 ch x 8 pad slots
    int c = t >> 3, i = t & 7;
    size_t off = (size_t)c * NSTR + (i < 4 ? i : (NND + i));  // 0..3 and NND+4..NND+7
    nfT[off] = 0.f;
}

// ---------------- K1: dilated conv1d — 8 nodes/thread (2 aligned quads), 8 outs/block
template <int D>
__device__ __forceinline__ void conv_body(const float* __restrict__ nfT,
                                          const float* __restrict__ wl,
                                          const int pq0, const int pq1,
                                          float acc[2][8][4])
{
    for (int c = 0; c < 128; c++) {
        const float* col = nfT + (size_t)c * NSTR + 4;
        float4 lo[2], mi[2], hi[2];
        lo[0] = *(const float4*)(col + pq0 - 4);
        mi[0] = *(const float4*)(col + pq0);
        hi[0] = *(const float4*)(col + pq0 + 4);
        lo[1] = *(const float4*)(col + pq1 - 4);
        mi[1] = *(const float4*)(col + pq1);
        hi[1] = *(const float4*)(col + pq1 + 4);
        float f0[2][4], f1[2][4], f2[2][4];
#pragma unroll
        for (int q = 0; q < 2; q++) {
            f1[q][0] = mi[q].x; f1[q][1] = mi[q].y; f1[q][2] = mi[q].z; f1[q][3] = mi[q].w;
            if (D == 1) {
                f0[q][0] = lo[q].w; f0[q][1] = mi[q].x; f0[q][2] = mi[q].y; f0[q][3] = mi[q].z;
                f2[q][0] = mi[q].y; f2[q][1] = mi[q].z; f2[q][2] = mi[q].w; f2[q][3] = hi[q].x;
            } else if (D == 2) {
                f0[q][0] = lo[q].z; f0[q][1] = lo[q].w; f0[q][2] = mi[q].x; f0[q][3] = mi[q].y;
                f2[q][0] = mi[q].z; f2[q][1] = mi[q].w; f2[q][2] = hi[q].x; f2[q][3] = hi[q].y;
            } else {
                f0[q][0] = lo[q].y; f0[q][1] = lo[q].z; f0[q][2] = lo[q].w; f0[q][3] = mi[q].x;
                f2[q][0] = mi[q].w; f2[q][1] = hi[q].x; f2[q][2] = hi[q].y; f2[q][3] = hi[q].z;
            }
        }
        const float4* w0 = (const float4*)&wl[(0 * 128 + c) * 8];
        const float4* w1 = (const float4*)&wl[(1 * 128 + c) * 8];
        const float4* w2 = (const float4*)&wl[(2 * 128 + c) * 8];
#pragma unroll
        for (int jh = 0; jh < 2; jh++) {
            float4 a0 = w0[jh], a1 = w1[jh], a2 = w2[jh];
#pragma unroll
            for (int q = 0; q < 2; q++)
#pragma unroll
                for (int i = 0; i < 4; i++) {
                    acc[q][jh * 4 + 0][i] += f0[q][i] * a0.x + f1[q][i] * a1.x + f2[q][i] * a2.x;
                    acc[q][jh * 4 + 1][i] += f0[q][i] * a0.y + f1[q][i] * a1.y + f2[q][i] * a2.y;
                    acc[q][jh * 4 + 2][i] += f0[q][i] * a0.z + f1[q][i] * a1.z + f2[q][i] * a2.z;
                    acc[q][jh * 4 + 3][i] += f0[q][i] * a0.w + f1[q][i] * a1.w + f2[q][i] * a2.w;
                }
        }
    }
}

__global__ __launch_bounds__(256, 3)
void conv_kernel(const float* __restrict__ nfT, const float* __restrict__ cw,
                 const float* __restrict__ cb, float* __restrict__ X)
{
    __shared__ __align__(16) float wl[3 * 128 * 8];   // [k][c][j] : 12 KB
    const int t  = threadIdx.x;
    const int og = blockIdx.y;   // 0..11 (group of 8 out channels)
    const int br = blockIdx.z;   // 0..2
    for (int l = t; l < 3 * 128 * 8; l += 256) {
        int j = l & 7; int c = (l >> 3) & 127; int k = l >> 10;
        wl[l] = cw[(((size_t)br * 96 + og * 8 + j) * 128 + c) * 3 + k];
    }
    __syncthreads();
    const int pq0 = blockIdx.x * 2048 + t * 4;
    const int pq1 = pq0 + 1024;
    float acc[2][8][4];
#pragma unroll
    for (int j = 0; j < 8; j++) {
        float b = cb[br * 96 + og * 8 + j];
#pragma unroll
        for (int q = 0; q < 2; q++)
#pragma unroll
            for (int i = 0; i < 4; i++) acc[q][j][i] = b;
    }
    if (br == 0)      conv_body<1>(nfT, wl, pq0, pq1, acc);
    else if (br == 1) conv_body<2>(nfT, wl, pq0, pq1, acc);
    else              conv_body<3>(nfT, wl, pq0, pq1, acc);
#pragma unroll
    for (int q = 0; q < 2; q++) {
        int pb = q ? pq1 : pq0;
#pragma unroll
        for (int i = 0; i < 4; i++) {
            int p = pb + i;
            if (p >= NND) continue;
            float* xo = X + (size_t)br * NND * 96 + (size_t)p * 96 + og * 8;
            float4 v0, v1;
            v0.x = acc[q][0][i]; v0.y = acc[q][1][i]; v0.z = acc[q][2][i]; v0.w = acc[q][3][i];
            v1.x = acc[q][4][i]; v1.y = acc[q][5][i]; v1.z = acc[q][6][i]; v1.w = acc[q][7][i];
            ((float4*)xo)[0] = v0;
            ((float4*)xo)[1] = v1;
        }
    }
}

// ---------------- K2: Y = relu(X_i)+X_{i+1} + BN1 stats (register accum) ----------
__global__ void y_stats_kernel(const float* __restrict__ X, float* __restrict__ Y,
                               float* __restrict__ st1)
{
    __shared__ float ls[384], lq[384];
    int t = threadIdx.x;
    int br = blockIdx.y, ip1 = (br + 1) % 3;
    int c = t % 96, rsub = t / 96;
    const size_t NM = (size_t)NND * 96;
    int r0 = blockIdx.x * 64;
    int rend = r0 + 64 < NND ? r0 + 64 : NND;
    float s = 0.f, q = 0.f;
    const float* Xa = X + (size_t)br * NM;
    const float* Xb = X + (size_t)ip1 * NM;
    float* Yb = Y + (size_t)br * NM;
    for (int r = r0 + rsub; r < rend; r += 4) {
        size_t idx = (size_t)r * 96 + c;
        float a = Xa[idx]; a = a > 0.f ? a : 0.f;
        float y = a + Xb[idx];
        Yb[idx] = y;
        s += y; q += y * y;
    }
    ls[t] = s; lq[t] = q;
    __syncthreads();
    if (t < 96) {
        s = ls[t] + ls[t + 96] + ls[t + 192] + ls[t + 288];
        q = lq[t] + lq[t + 96] + lq[t + 192] + lq[t + 288];
        unsafeAtomicAdd(&st1[br * 96 + t], s);
        unsafeAtomicAdd(&st1[288 + br * 96 + t], q);
    }
}

// ---------------- BN finalize ----------------
__global__ void bn_finalize_kernel(const float* __restrict__ st, const float* __restrict__ g,
                                   const float* __restrict__ b,
                                   float* __restrict__ sc, float* __restrict__ sh,
                                   int C, int gmod)
{
    int t = threadIdx.x;
    if (t >= C) return;
    float mean = st[t] / (float)NND;
    float var  = st[C + t] / (float)NND - mean * mean;
    float rs = rsqrtf(var + EPSV);
    float gg = g[t % gmod], bb = b[t % gmod];
    float s = gg * rs;
    sc[t] = s; sh[t] = bb - mean * s;
}

// ---------------- K4: pull GCN aggregate, 3 branches fused, float4 channels ------
__global__ void pull_bn_kernel(const float* __restrict__ Y, const int* __restrict__ rowptr,
                               const int* __restrict__ csrs, const float* __restrict__ csrw,
                               const float* __restrict__ sc1, const float* __restrict__ sh1,
                               float* __restrict__ AGG)
{
    int id = blockIdx.x * 256 + threadIdx.x;
    if (id >= NND * 24) return;
    int p = id / 24, q = id % 24;
    const float4* Y4 = (const float4*)Y;
    const size_t NQ = (size_t)NND * 24;
    int beg = rowptr[p], end = rowptr[p + 1];
    float a0x=0,a0y=0,a0z=0,a0w=0, a1x=0,a1y=0,a1z=0,a1w=0, a2x=0,a2y=0,a2z=0,a2w=0;
    float wsum = 0.f;
    for (int i = beg; i < end; i++) {
        float w = csrw[i];
        size_t off = (size_t)csrs[i] * 24 + q;
        float4 v0 = Y4[off];
        float4 v1 = Y4[NQ + off];
        float4 v2 = Y4[2 * NQ + off];
        a0x += w * v0.x; a0y += w * v0.y; a0z += w * v0.z; a0w += w * v0.w;
        a1x += w * v1.x; a1y += w * v1.y; a1z += w * v1.z; a1w += w * v1.w;
        a2x += w * v2.x; a2y += w * v2.y; a2z += w * v2.z; a2w += w * v2.w;
        wsum += w;
    }
    const float4* S4 = (const float4*)sc1;
    const float4* H4 = (const float4*)sh1;
    float4* AG4 = (float4*)AGG;
    size_t ob = (size_t)p * 24 + q;
    {
        float4 s = S4[q], h = H4[q], r;
        r.x = s.x * a0x + h.x * wsum; r.y = s.y * a0y + h.y * wsum;
        r.z = s.z * a0z + h.z * wsum; r.w = s.w * a0w + h.w * wsum;
        AG4[ob] = r;
    }
    {
        float4 s = S4[24 + q], h = H4[24 + q], r;
        r.x = s.x * a1x + h.x * wsum; r.y = s.y * a1y + h.y * wsum;
        r.z = s.z * a1z + h.z * wsum; r.w = s.w * a1w + h.w * wsum;
        AG4[NQ + ob] = r;
    }
    {
        float4 s = S4[48 + q], h = H4[48 + q], r;
        r.x = s.x * a2x + h.x * wsum; r.y = s.y * a2y + h.y * wsum;
        r.z = s.z * a2z + h.z * wsum; r.w = s.w * a2w + h.w * wsum;
        AG4[2 * NQ + ob] = r;
    }
}

// ---------------- pull gather, float2-vectorized (C even) ----------------
template <int C>
__global__ void pull2_kernel(const float* __restrict__ in, const int* __restrict__ rowptr,
                             const int* __restrict__ csrs, const float* __restrict__ csrw,
                             float* __restrict__ out)
{
    constexpr int C2 = C / 2;
    int id = blockIdx.x * 256 + threadIdx.x;
    if (id >= NND * C2) return;
    int p = id / C2, q = id % C2;
    const float2* in2 = (const float2*)in;
    int beg = rowptr[p], end = rowptr[p + 1];
    float ax = 0.f, ay = 0.f;
    for (int i = beg; i < end; i++) {
        float w = csrw[i];
        float2 v = in2[(size_t)csrs[i] * C2 + q];
        ax += w * v.x; ay += w * v.y;
    }
    float2 r; r.x = ax; r.y = ay;
    ((float2*)out)[(size_t)p * C2 + q] = r;
}

// ---------------- pull gather, scalar (odd C) ----------------
template <int C>
__global__ void pull_kernel(const float* __restrict__ in, const int* __restrict__ rowptr,
                            const int* __restrict__ csrs, const float* __restrict__ csrw,
                            float* __restrict__ out)
{
    int id = blockIdx.x * 256 + threadIdx.x;
    if (id >= NND * C) return;
    int p = id / C, c = id % C;
    int beg = rowptr[p], end = rowptr[p + 1];
    float acc = 0.f;
    for (int i = beg; i < end; i++)
        acc += csrw[i] * in[(size_t)csrs[i] * C + c];
    out[id] = acc;
}

// ---------------- generic small matmul + bias + relu ----------------
__global__ void matmul_relu_kernel(const float* __restrict__ in, const float* __restrict__ W,
                                   const float* __restrict__ bias, float* __restrict__ out,
                                   int Cin, int Cout)
{
    int id = blockIdx.x * 256 + threadIdx.x;
    if (id >= NND * Cout) return;
    int p = id / Cout, o = id % Cout;
    float acc = bias[o];
    const float* row = in + (size_t)p * Cin;
    for (int c = 0; c < Cin; c++) acc += row[c] * W[c * Cout + o];
    out[id] = acc > 0.f ? acc : 0.f;
}

// ---------------- GCN matmul 96->54, 3 branches in one launch ----------------
__global__ void matmul3_relu_kernel(const float* __restrict__ AGG, const float* __restrict__ gw,
                                    const float* __restrict__ gb, float* __restrict__ H2c)
{
    int id = blockIdx.x * 256 + threadIdx.x;
    if (id >= NND * 54) return;
    int br = blockIdx.y;
    int p = id / 54, o = id % 54;
    const float* W = gw + (size_t)br * 96 * 54;
    float acc = gb[br * 54 + o];
    const float* row = AGG + (size_t)br * NND * 96 + (size_t)p * 96;
    for (int c = 0; c < 96; c++) acc += row[c] * W[c * 54 + o];
    H2c[(size_t)br * NND * 54 + id] = acc > 0.f ? acc : 0.f;
}

// ---------------- K6: press conv (3ch,K=3,SAME over 54) + BN2 stats ----------------
__global__ void press_stats_kernel(const float* __restrict__ H2, const float* __restrict__ pw,
                                   const float* __restrict__ pb, float* __restrict__ PRS,
                                   float* __restrict__ st2)
{
    __shared__ float ls[54], lq[54];
    int t = threadIdx.x;
    if (t < 54) { ls[t] = 0.f; lq[t] = 0.f; }
    __syncthreads();
    float pwf[9];
#pragma unroll
    for (int q = 0; q < 9; q++) pwf[q] = pw[q];
    float pbf = pb[0];
    const size_t NM = (size_t)NND * 54;
    size_t base = (size_t)blockIdx.x * 6912;
    for (int q = 0; q < 27; q++) {
        size_t idx = base + q * 256 + t;
        if (idx < NM) {
            int p = (int)(idx / 54), h = (int)(idx % 54);
            float sum = pbf;
#pragma unroll
            for (int i = 0; i < 3; i++)
#pragma unroll
                for (int k = 0; k < 3; k++) {
                    int hh = h + k - 1;
                    if (hh >= 0 && hh < 54)
                        sum += pwf[i * 3 + k] * H2[(size_t)i * NM + (size_t)p * 54 + hh];
                }
            PRS[idx] = sum;
            atomicAdd(&ls[h], sum); atomicAdd(&lq[h], sum * sum);
        }
    }
    __syncthreads();
    if (t < 54) {
        unsafeAtomicAdd(&st2[t], ls[t]);
        unsafeAtomicAdd(&st2[54 + t], lq[t]);
    }
}

// ---------------- K8: emd = affine(pressed) ----------------
__global__ void emd_kernel(float* __restrict__ PRS, const float* __restrict__ sc2,
                           const float* __restrict__ sh2, float* __restrict__ outp)
{
    int id = blockIdx.x * 256 + threadIdx.x;
    if (id >= NND * 54) return;
    int h = id % 54;
    float v = PRS[id] * sc2[h] + sh2[h];
    PRS[id] = v;
    outp[id] = v;
}

// ---------------- K15: graph pooling, block per graph, no atomics ----------------
__global__ void pool_kernel(const float* __restrict__ H1, const float* __restrict__ H2j,
                            const float* __restrict__ H3, const int* __restrict__ gr,
                            float* __restrict__ HG)
{
    __shared__ float part[4][75];
    int t = threadIdx.x;   // 300 = 75 x 4
    int c = t % 75, sub = t / 75;
    int g = blockIdx.x;
    int s = gr[g], e = gr[g + 1];
    float acc = 0.f;
    for (int p = s + sub; p < e; p += 4) {
        float v;
        if (c < 34)      v = H1[(size_t)p * 34 + c];
        else if (c < 59) v = H2j[(size_t)p * 25 + (c - 34)];
        else             v = H3[(size_t)p * 16 + (c - 59)];
        acc += v;
    }
    part[sub][c] = acc;
    __syncthreads();
    if (t < 75) HG[g * 75 + t] = part[0][t] + part[1][t] + part[2][t] + part[3][t];
}

// ---------------- K16: BN3 + cls matmuls, single block ----------------
__global__ void final_kernel(const float* __restrict__ HG, const float* __restrict__ g3,
                             const float* __restrict__ b3,
                             const float* __restrict__ w1, const float* __restrict__ b1,
                             const float* __restrict__ w2, const float* __restrict__ b2,
                             float* __restrict__ outp)
{
    __shared__ float hg[64 * 75];
    __shared__ float o1[64 * 120];
    __shared__ float sc[75], sh[75];
    int t = threadIdx.x;   // 512
    for (int idx = t; idx < 64 * 75; idx += 512) hg[idx] = HG[idx];
    __syncthreads();
    if (t < 75) {
        float s = 0.f, q = 0.f;
        for (int r = 0; r < 64; r++) { float v = hg[r * 75 + t]; s += v; q += v * v; }
        float m = s / 64.f, var = q / 64.f - m * m;
        float rs = rsqrtf(var + EPSV);
        float scale = g3[t] * rs;
        sc[t] = scale; sh[t] = b3[t] - m * scale;
    }
    __syncthreads();
    for (int idx = t; idx < 64 * 75; idx += 512) { int c = idx % 75; hg[idx] = hg[idx] * sc[c] + sh[c]; }
    __syncthreads();
    for (int idx = t; idx < 64 * 120; idx += 512) {
        int r = idx / 120, o = idx % 120;
        float a = b1[o];
        for (int c = 0; c < 75; c++) a += hg[r * 75 + c] * w1[c * 120 + o];
        o1[idx] = a;
    }
    __syncthreads();
    for (int idx = t; idx < 640; idx += 512) {
        int r = idx / 10, o = idx % 10;
        float a = b2[o];
        for (int k = 0; k < 120; k++) a += o1[r * 120 + k] * w2[k * 10 + o];
        outp[idx] = a;
    }
}

extern "C" void kernel_launch(void* const* d_in, const int* in_sizes, int n_in,
                              void* d_out, int out_size, void* d_ws, size_t ws_size,
                              hipStream_t stream)
{
    (void)in_sizes; (void)n_in; (void)out_size;
    const float* nf     = (const float*)d_in[0];
    const float* ew     = (const float*)d_in[1];
    const float* conv_w = (const float*)d_in[2];
    const float* conv_b = (const float*)d_in[3];
    const float* gcn_w  = (const float*)d_in[4];
    const float* gcn_b  = (const float*)d_in[5];
    const float* bn1_g = (const float*)d_in[6],  *bn1_b = (const float*)d_in[7];
    const float* bn2_g = (const float*)d_in[8],  *bn2_b = (const float*)d_in[9];
    const float* bn3_g = (const float*)d_in[10], *bn3_b = (const float*)d_in[11];
    const float* press_w = (const float*)d_in[12], *press_b = (const float*)d_in[13];
    const float* jk_w1 = (const float*)d_in[14], *jk_b1 = (const float*)d_in[15];
    const float* jk_w2 = (const float*)d_in[16], *jk_b2 = (const float*)d_in[17];
    const float* jk_w3 = (const float*)d_in[18], *jk_b3 = (const float*)d_in[19];
    const float* cls1_w = (const float*)d_in[20], *cls1_b = (const float*)d_in[21];
    const float* cls2_w = (const float*)d_in[22], *cls2_b = (const float*)d_in[23];
    const int* esrc = (const int*)d_in[24];
    const int* edst = (const int*)d_in[25];
    const int* gid  = (const int*)d_in[26];
    float* out = (float*)d_out;   // fp32 outputs: (logits[640], emd[2.7M])

    float* ws = (float*)d_ws;
    const size_t NM = (size_t)NND * 96;
    const size_t N54 = (size_t)NND * 54;
    float* X   = ws;                 // 3*NM   (aliased later: AGG)
    float* Y   = X + 3 * NM;         // 3*NM   (nfT during conv; jk buffers later)
    float* H2c = Y + 3 * NM;         // 3*N54
    float* PRS = H2c + 3 * N54;      // N54
    float* ST1 = PRS + N54;          // 576
    float* SC1 = ST1 + 576;          // 288
    float* SH1 = SC1 + 288;          // 288
    float* ST2 = SH1 + 288;          // 108
    float* SC2 = ST2 + 108;          // 54
    float* SH2 = SC2 + 54;           // 54
    float* HG  = SH2 + 54;           // 4800
    // CSR-by-dst + pooling scratch
    int* CNT    = (int*)(HG + 4800);     // 50000
    int* ROWPTR = CNT + NND;             // 50001
    int* CURSOR = ROWPTR + NND + 1;      // 50000
    int* CSRS   = CURSOR + NND;          // 800000
    float* CSRW = (float*)(CSRS + NED);  // 800000
    int* BSUM   = (int*)(CSRW + NED);    // 64 (49 used)
    int* GR     = BSUM + 64;             // 65
    size_t need = (size_t)((float*)(GR + 65) - ws) * sizeof(float);
    if (ws_size < need) return;      // ws too small -> fail loudly in validation

    // aliases
    float* nfT  = Y;                 // [128][NSTR] padded — dead before y_stats writes Y
    float* AGG  = X;
    float* AGG1 = Y;                           // N*54
    float* H1j  = AGG1 + N54;                  // N*34
    float* AGG2 = H1j + (size_t)NND * 34;      // N*34
    float* H2j  = AGG2 + (size_t)NND * 34;     // N*25
    float* AGG3 = H2j + (size_t)NND * 25;      // N*25
    float* H3j  = AGG3 + (size_t)NND * 25;     // N*16

    // zero stats (ST1..SH2 = 1368 floats) and CSR histogram
    hipMemsetAsync(ST1, 0, 1368 * sizeof(float), stream);
    hipMemsetAsync(CNT, 0, NND * sizeof(int), stream);

    // CSR build (multi-block scan) + graph ranges
    hist_kernel<<<(NED + 255) / 256, 256, 0, stream>>>(edst, CNT);
    scanA_kernel<<<49, 256, 0, stream>>>(CNT, BSUM);
    scanB_kernel<<<1, 64, 0, stream>>>(BSUM, ROWPTR, 49);
    scanC_kernel<<<49, 1024, 0, stream>>>(CNT, BSUM, ROWPTR, CURSOR);
    fill_kernel<<<(NED + 255) / 256, 256, 0, stream>>>(esrc, edst, ew, CURSOR, CSRS, CSRW);
    grstart_kernel<<<1, 128, 0, stream>>>(gid, GR);

    // K0: transpose node feats into padded [c][4+p] + zero guard bands
    transpose_kernel<<<dim3((NND + 31) / 32, 4), 256, 0, stream>>>(nf, nfT);
    pad_kernel<<<1, 1024, 0, stream>>>(nfT);

    // K1: dilated convs — 8 nodes/thread as 2 aligned quads, 8 outs/block
    conv_kernel<<<dim3(25, 12, 3), 256, 0, stream>>>(nfT, conv_w, conv_b, X);

    // K2/K3: Y + BN1   (overwrites nfT region — conv already done)
    y_stats_kernel<<<dim3((NND + 63) / 64, 3), 384, 0, stream>>>(X, Y, ST1);
    bn_finalize_kernel<<<1, 512, 0, stream>>>(ST1, bn1_g, bn1_b, SC1, SH1, 288, 96);

    // K4: pull GCN aggregate, 3 branches fused, float4 channels
    pull_bn_kernel<<<(NND * 24 + 255) / 256, 256, 0, stream>>>(
        Y, ROWPTR, CSRS, CSRW, SC1, SH1, AGG);

    // K5: GCN matmul + relu, all 3 branches in one launch
    matmul3_relu_kernel<<<dim3((int)((N54 + 255) / 256), 3), 256, 0, stream>>>(
        AGG, gcn_w, gcn_b, H2c);

    // K6/K7/K8: press + BN2 + emd out (fp32 at element offset 640)
    press_stats_kernel<<<(int)((N54 + 6911) / 6912), 256, 0, stream>>>(H2c, press_w, press_b, PRS, ST2);
    bn_finalize_kernel<<<1, 512, 0, stream>>>(ST2, bn2_g, bn2_b, SC2, SH2, 54, 54);
    emd_kernel<<<(int)((N54 + 255) / 256), 256, 0, stream>>>(PRS, SC2, SH2, out + 640);

    // JK layer 1 (Y region dead -> jk buffers)
    pull2_kernel<54><<<(NND * 27 + 255) / 256, 256, 0, stream>>>(PRS, ROWPTR, CSRS, CSRW, AGG1);
    matmul_relu_kernel<<<(NND * 34 + 255) / 256, 256, 0, stream>>>(AGG1, jk_w1, jk_b1, H1j, 54, 34);

    // JK layer 2
    pull2_kernel<34><<<(NND * 17 + 255) / 256, 256, 0, stream>>>(H1j, ROWPTR, CSRS, CSRW, AGG2);
    matmul_relu_kernel<<<(NND * 25 + 255) / 256, 256, 0, stream>>>(AGG2, jk_w2, jk_b2, H2j, 34, 25);

    // JK layer 3
    pull_kernel<25><<<(NND * 25 + 255) / 256, 256, 0, stream>>>(H2j, ROWPTR, CSRS, CSRW, AGG3);
    matmul_relu_kernel<<<(NND * 16 + 255) / 256, 256, 0, stream>>>(AGG3, jk_w3, jk_b3, H3j, 25, 16);

    // pooling (block per graph, no atomics) + final
    pool_kernel<<<NGR, 300, 0, stream>>>(H1j, H2j, H3j, GR, HG);
    final_kernel<<<1, 512, 0, stream>>>(HG, bn3_g, bn3_b, cls1_w, cls1_b, cls2_w, cls2_b, out);
}

// Round 9
// 1020.269 us; speedup vs baseline: 1.8219x; 1.2197x over previous
//
#include <hip/hip_runtime.h>
#include <hip/hip_bf16.h>

#define NND 50000
#define NED 800000
#define NGR 64
#define EPSV 1e-5f
#define NSTR (NND + 8)   // padded column stride for nfT (4-elem zero guards)

// ---------------- CSR build: histogram / 3-phase scan / fill ----------------
__global__ void hist_kernel(const int* __restrict__ dst, int* __restrict__ cnt)
{
    int e = blockIdx.x * 256 + threadIdx.x;
    if (e < NED) atomicAdd(&cnt[dst[e]], 1);
}

__global__ void scanA_kernel(const int* __restrict__ cnt, int* __restrict__ bsum)
{
    __shared__ int buf[256];
    int t = threadIdx.x, base = blockIdx.x * 1024;
    int s = 0;
    for (int i = t; i < 1024; i += 256) {
        int idx = base + i;
        s += (idx < NND) ? cnt[idx] : 0;
    }
    buf[t] = s; __syncthreads();
    for (int off = 128; off; off >>= 1) {
        if (t < off) buf[t] += buf[t + off];
        __syncthreads();
    }
    if (t == 0) bsum[blockIdx.x] = buf[0];
}

__global__ void scanB_kernel(int* __restrict__ bsum, int* __restrict__ rowptr, int nb)
{
    if (threadIdx.x == 0) {
        int acc = 0;
        for (int i = 0; i < nb; i++) { int v = bsum[i]; bsum[i] = acc; acc += v; }
        rowptr[NND] = acc;
    }
}

__global__ void scanC_kernel(const int* __restrict__ cnt, const int* __restrict__ bsum,
                             int* __restrict__ rowptr, int* __restrict__ cursor)
{
    __shared__ int buf[1024];
    int t = threadIdx.x, idx = blockIdx.x * 1024 + t;
    int v = (idx < NND) ? cnt[idx] : 0;
    buf[t] = v; __syncthreads();
    for (int off = 1; off < 1024; off <<= 1) {
        int x = (t >= off) ? buf[t - off] : 0;
        __syncthreads();
        buf[t] += x;
        __syncthreads();
    }
    if (idx < NND) {
        int excl = buf[t] - v + bsum[blockIdx.x];
        rowptr[idx] = excl; cursor[idx] = excl;
    }
}

__global__ void fill_kernel(const int* __restrict__ src, const int* __restrict__ dst,
                            const float* __restrict__ ew, int* __restrict__ cursor,
                            int* __restrict__ csrs, float* __restrict__ csrw)
{
    int e = blockIdx.x * 256 + threadIdx.x;
    if (e < NED) {
        int pos = atomicAdd(&cursor[dst[e]], 1);
        csrs[pos] = src[e];
        csrw[pos] = ew[e];
    }
}

// ---------------- graph ranges via binary search on sorted graph_ids ----------------
__global__ void grstart_kernel(const int* __restrict__ gid, int* __restrict__ gr)
{
    int t = threadIdx.x;
    if (t > NGR) return;
    if (t == NGR) { gr[NGR] = NND; return; }
    int lo = 0, hi = NND;
    while (lo < hi) { int mid = (lo + hi) >> 1; if (gid[mid] < t) lo = mid + 1; else hi = mid; }
    gr[t] = lo;
}

// ---------------- K0: transpose node_feats [p][c] -> nfT [c][4+p] (padded) ---------
__global__ void transpose_kernel(const float* __restrict__ nf, float* __restrict__ nfT)
{
    __shared__ float tile[32][33];
    int tx = threadIdx.x & 31, ty = threadIdx.x >> 5;   // 32 x 8
    int p0 = blockIdx.x * 32, c0 = blockIdx.y * 32;
#pragma unroll
    for (int i = 0; i < 4; i++) {
        int p = p0 + ty + i * 8;
        if (p < NND) tile[ty + i * 8][tx] = nf[(size_t)p * 128 + c0 + tx];
    }
    __syncthreads();
#pragma unroll
    for (int i = 0; i < 4; i++) {
        int c = c0 + ty + i * 8;
        int p = p0 + tx;
        if (p < NND) nfT[(size_t)c * NSTR + 4 + p] = tile[tx][ty + i * 8];
    }
}

// zero the 4-elem guard bands of each padded column
__global__ void pad_kernel(float* __restrict__ nfT)
{
    int t = threadIdx.x;           // 1024 = 128 ch x 8 pad slots
    int c = t >> 3, i = t & 7;
    size_t off = (size_t)c * NSTR + (i < 4 ? i : (NND + i));  // 0..3 and NND+4..NND+7
    nfT[off] = 0.f;
}

// ---------------- K1: dilated conv1d — 8 nodes/thread (2 aligned quads), 8 outs/block
template <int D>
__device__ __forceinline__ void conv_body(const float* __restrict__ nfT,
                                          const float* __restrict__ wl,
                                          const int pq0, const int pq1,
                                          float acc[2][8][4])
{
    for (int c = 0; c < 128; c++) {
        const float* col = nfT + (size_t)c * NSTR + 4;
        float4 lo[2], mi[2], hi[2];
        lo[0] = *(const float4*)(col + pq0 - 4);
        mi[0] = *(const float4*)(col + pq0);
        hi[0] = *(const float4*)(col + pq0 + 4);
        lo[1] = *(const float4*)(col + pq1 - 4);
        mi[1] = *(const float4*)(col + pq1);
        hi[1] = *(const float4*)(col + pq1 + 4);
        float f0[2][4], f1[2][4], f2[2][4];
#pragma unroll
        for (int q = 0; q < 2; q++) {
            f1[q][0] = mi[q].x; f1[q][1] = mi[q].y; f1[q][2] = mi[q].z; f1[q][3] = mi[q].w;
            if (D == 1) {
                f0[q][0] = lo[q].w; f0[q][1] = mi[q].x; f0[q][2] = mi[q].y; f0[q][3] = mi[q].z;
                f2[q][0] = mi[q].y; f2[q][1] = mi[q].z; f2[q][2] = mi[q].w; f2[q][3] = hi[q].x;
            } else if (D == 2) {
                f0[q][0] = lo[q].z; f0[q][1] = lo[q].w; f0[q][2] = mi[q].x; f0[q][3] = mi[q].y;
                f2[q][0] = mi[q].z; f2[q][1] = mi[q].w; f2[q][2] = hi[q].x; f2[q][3] = hi[q].y;
            } else {
                f0[q][0] = lo[q].y; f0[q][1] = lo[q].z; f0[q][2] = lo[q].w; f0[q][3] = mi[q].x;
                f2[q][0] = mi[q].w; f2[q][1] = hi[q].x; f2[q][2] = hi[q].y; f2[q][3] = hi[q].z;
            }
        }
        const float4* w0 = (const float4*)&wl[(0 * 128 + c) * 8];
        const float4* w1 = (const float4*)&wl[(1 * 128 + c) * 8];
        const float4* w2 = (const float4*)&wl[(2 * 128 + c) * 8];
#pragma unroll
        for (int jh = 0; jh < 2; jh++) {
            float4 a0 = w0[jh], a1 = w1[jh], a2 = w2[jh];
#pragma unroll
            for (int q = 0; q < 2; q++)
#pragma unroll
                for (int i = 0; i < 4; i++) {
                    acc[q][jh * 4 + 0][i] += f0[q][i] * a0.x + f1[q][i] * a1.x + f2[q][i] * a2.x;
                    acc[q][jh * 4 + 1][i] += f0[q][i] * a0.y + f1[q][i] * a1.y + f2[q][i] * a2.y;
                    acc[q][jh * 4 + 2][i] += f0[q][i] * a0.z + f1[q][i] * a1.z + f2[q][i] * a2.z;
                    acc[q][jh * 4 + 3][i] += f0[q][i] * a0.w + f1[q][i] * a1.w + f2[q][i] * a2.w;
                }
        }
    }
}

__global__ __launch_bounds__(256, 3)
void conv_kernel(const float* __restrict__ nfT, const float* __restrict__ cw,
                 const float* __restrict__ cb, float* __restrict__ X)
{
    __shared__ __align__(16) float wl[3 * 128 * 8];   // [k][c][j] : 12 KB
    const int t  = threadIdx.x;
    const int og = blockIdx.y;   // 0..11 (group of 8 out channels)
    const int br = blockIdx.z;   // 0..2
    for (int l = t; l < 3 * 128 * 8; l += 256) {
        int j = l & 7; int c = (l >> 3) & 127; int k = l >> 10;
        wl[l] = cw[(((size_t)br * 96 + og * 8 + j) * 128 + c) * 3 + k];
    }
    __syncthreads();
    const int pq0 = blockIdx.x * 2048 + t * 4;
    const int pq1 = pq0 + 1024;
    float acc[2][8][4];
#pragma unroll
    for (int j = 0; j < 8; j++) {
        float b = cb[br * 96 + og * 8 + j];
#pragma unroll
        for (int q = 0; q < 2; q++)
#pragma unroll
            for (int i = 0; i < 4; i++) acc[q][j][i] = b;
    }
    if (br == 0)      conv_body<1>(nfT, wl, pq0, pq1, acc);
    else if (br == 1) conv_body<2>(nfT, wl, pq0, pq1, acc);
    else              conv_body<3>(nfT, wl, pq0, pq1, acc);
#pragma unroll
    for (int q = 0; q < 2; q++) {
        int pb = q ? pq1 : pq0;
#pragma unroll
        for (int i = 0; i < 4; i++) {
            int p = pb + i;
            if (p >= NND) continue;
            float* xo = X + (size_t)br * NND * 96 + (size_t)p * 96 + og * 8;
            float4 v0, v1;
            v0.x = acc[q][0][i]; v0.y = acc[q][1][i]; v0.z = acc[q][2][i]; v0.w = acc[q][3][i];
            v1.x = acc[q][4][i]; v1.y = acc[q][5][i]; v1.z = acc[q][6][i]; v1.w = acc[q][7][i];
            ((float4*)xo)[0] = v0;
            ((float4*)xo)[1] = v1;
        }
    }
}

// ---------------- K2: Y = relu(X_i)+X_{i+1} + BN1 stats (register accum) ----------
__global__ void y_stats_kernel(const float* __restrict__ X, float* __restrict__ Y,
                               float* __restrict__ st1)
{
    __shared__ float ls[384], lq[384];
    int t = threadIdx.x;
    int br = blockIdx.y, ip1 = (br + 1) % 3;
    int c = t % 96, rsub = t / 96;
    const size_t NM = (size_t)NND * 96;
    int r0 = blockIdx.x * 64;
    int rend = r0 + 64 < NND ? r0 + 64 : NND;
    float s = 0.f, q = 0.f;
    const float* Xa = X + (size_t)br * NM;
    const float* Xb = X + (size_t)ip1 * NM;
    float* Yb = Y + (size_t)br * NM;
    for (int r = r0 + rsub; r < rend; r += 4) {
        size_t idx = (size_t)r * 96 + c;
        float a = Xa[idx]; a = a > 0.f ? a : 0.f;
        float y = a + Xb[idx];
        Yb[idx] = y;
        s += y; q += y * y;
    }
    ls[t] = s; lq[t] = q;
    __syncthreads();
    if (t < 96) {
        s = ls[t] + ls[t + 96] + ls[t + 192] + ls[t + 288];
        q = lq[t] + lq[t + 96] + lq[t + 192] + lq[t + 288];
        unsafeAtomicAdd(&st1[br * 96 + t], s);
        unsafeAtomicAdd(&st1[288 + br * 96 + t], q);
    }
}

// ---------------- BN finalize ----------------
__global__ void bn_finalize_kernel(const float* __restrict__ st, const float* __restrict__ g,
                                   const float* __restrict__ b,
                                   float* __restrict__ sc, float* __restrict__ sh,
                                   int C, int gmod)
{
    int t = threadIdx.x;
    if (t >= C) return;
    float mean = st[t] / (float)NND;
    float var  = st[C + t] / (float)NND - mean * mean;
    float rs = rsqrtf(var + EPSV);
    float gg = g[t % gmod], bb = b[t % gmod];
    float s = gg * rs;
    sc[t] = s; sh[t] = bb - mean * s;
}

// ---------------- K4: pull GCN aggregate, 3 branches fused, float4 channels ------
__global__ void pull_bn_kernel(const float* __restrict__ Y, const int* __restrict__ rowptr,
                               const int* __restrict__ csrs, const float* __restrict__ csrw,
                               const float* __restrict__ sc1, const float* __restrict__ sh1,
                               float* __restrict__ AGG)
{
    int id = blockIdx.x * 256 + threadIdx.x;
    if (id >= NND * 24) return;
    int p = id / 24, q = id % 24;
    const float4* Y4 = (const float4*)Y;
    const size_t NQ = (size_t)NND * 24;
    int beg = rowptr[p], end = rowptr[p + 1];
    float a0x=0,a0y=0,a0z=0,a0w=0, a1x=0,a1y=0,a1z=0,a1w=0, a2x=0,a2y=0,a2z=0,a2w=0;
    float wsum = 0.f;
    for (int i = beg; i < end; i++) {
        float w = csrw[i];
        size_t off = (size_t)csrs[i] * 24 + q;
        float4 v0 = Y4[off];
        float4 v1 = Y4[NQ + off];
        float4 v2 = Y4[2 * NQ + off];
        a0x += w * v0.x; a0y += w * v0.y; a0z += w * v0.z; a0w += w * v0.w;
        a1x += w * v1.x; a1y += w * v1.y; a1z += w * v1.z; a1w += w * v1.w;
        a2x += w * v2.x; a2y += w * v2.y; a2z += w * v2.z; a2w += w * v2.w;
        wsum += w;
    }
    const float4* S4 = (const float4*)sc1;
    const float4* H4 = (const float4*)sh1;
    float4* AG4 = (float4*)AGG;
    size_t ob = (size_t)p * 24 + q;
    {
        float4 s = S4[q], h = H4[q], r;
        r.x = s.x * a0x + h.x * wsum; r.y = s.y * a0y + h.y * wsum;
        r.z = s.z * a0z + h.z * wsum; r.w = s.w * a0w + h.w * wsum;
        AG4[ob] = r;
    }
    {
        float4 s = S4[24 + q], h = H4[24 + q], r;
        r.x = s.x * a1x + h.x * wsum; r.y = s.y * a1y + h.y * wsum;
        r.z = s.z * a1z + h.z * wsum; r.w = s.w * a1w + h.w * wsum;
        AG4[NQ + ob] = r;
    }
    {
        float4 s = S4[48 + q], h = H4[48 + q], r;
        r.x = s.x * a2x + h.x * wsum; r.y = s.y * a2y + h.y * wsum;
        r.z = s.z * a2z + h.z * wsum; r.w = s.w * a2w + h.w * wsum;
        AG4[2 * NQ + ob] = r;
    }
}

// ---------------- pull gather, float2-vectorized (C even) ----------------
template <int C>
__global__ void pull2_kernel(const float* __restrict__ in, const int* __restrict__ rowptr,
                             const int* __restrict__ csrs, const float* __restrict__ csrw,
                             float* __restrict__ out)
{
    constexpr int C2 = C / 2;
    int id = blockIdx.x * 256 + threadIdx.x;
    if (id >= NND * C2) return;
    int p = id / C2, q = id % C2;
    const float2* in2 = (const float2*)in;
    int beg = rowptr[p], end = rowptr[p + 1];
    float ax = 0.f, ay = 0.f;
    for (int i = beg; i < end; i++) {
        float w = csrw[i];
        float2 v = in2[(size_t)csrs[i] * C2 + q];
        ax += w * v.x; ay += w * v.y;
    }
    float2 r; r.x = ax; r.y = ay;
    ((float2*)out)[(size_t)p * C2 + q] = r;
}

// ---------------- pull gather, scalar (odd C) ----------------
template <int C>
__global__ void pull_kernel(const float* __restrict__ in, const int* __restrict__ rowptr,
                            const int* __restrict__ csrs, const float* __restrict__ csrw,
                            float* __restrict__ out)
{
    int id = blockIdx.x * 256 + threadIdx.x;
    if (id >= NND * C) return;
    int p = id / C, c = id % C;
    int beg = rowptr[p], end = rowptr[p + 1];
    float acc = 0.f;
    for (int i = beg; i < end; i++)
        acc += csrw[i] * in[(size_t)csrs[i] * C + c];
    out[id] = acc;
}

// ---------------- node-per-thread matmul + bias + relu, W staged in LDS ----------
// thread p: acc[CoutP] in regs; row streamed as float4/float2/scalar; W via
// wave-uniform LDS b128 broadcasts. nbr: branch count (gridDim.y), W/b strided.
template <int Cin, int Cout>
__global__ __launch_bounds__(128)
void matmul_node_kernel(const float* __restrict__ in, const float* __restrict__ W,
                        const float* __restrict__ bias, float* __restrict__ out)
{
    constexpr int CoutP = (Cout + 3) & ~3;
    __shared__ __align__(16) float wl[Cin * CoutP];
    __shared__ float bl[CoutP];
    const int t = threadIdx.x;
    const int br = blockIdx.y;
    const float* Wb = W + (size_t)br * Cin * Cout;
    for (int l = t; l < Cin * CoutP; l += 128) {
        int c = l / CoutP, o = l % CoutP;
        wl[l] = (o < Cout) ? Wb[c * Cout + o] : 0.f;
    }
    if (t < CoutP) bl[t] = (t < Cout) ? bias[br * Cout + t] : 0.f;
    __syncthreads();
    int p = blockIdx.x * 128 + t;
    if (p >= NND) return;
    float acc[CoutP];
#pragma unroll
    for (int o = 0; o < CoutP; o++) acc[o] = bl[o];
    const float* row = in + (size_t)br * NND * Cin + (size_t)p * Cin;
    if constexpr (Cin % 4 == 0) {
        const float4* row4 = (const float4*)row;
#pragma unroll
        for (int c4 = 0; c4 < Cin / 4; c4++) {
            float4 f4 = row4[c4];
            float fv[4] = {f4.x, f4.y, f4.z, f4.w};
#pragma unroll
            for (int cc = 0; cc < 4; cc++) {
                const float4* w4 = (const float4*)&wl[(c4 * 4 + cc) * CoutP];
#pragma unroll
                for (int oq = 0; oq < CoutP / 4; oq++) {
                    float4 wv = w4[oq];
                    acc[oq * 4 + 0] += fv[cc] * wv.x;
                    acc[oq * 4 + 1] += fv[cc] * wv.y;
                    acc[oq * 4 + 2] += fv[cc] * wv.z;
                    acc[oq * 4 + 3] += fv[cc] * wv.w;
                }
            }
        }
    } else if constexpr (Cin % 2 == 0) {
        const float2* row2 = (const float2*)row;
#pragma unroll
        for (int c2 = 0; c2 < Cin / 2; c2++) {
            float2 f2 = row2[c2];
            float fv[2] = {f2.x, f2.y};
#pragma unroll
            for (int cc = 0; cc < 2; cc++) {
                const float4* w4 = (const float4*)&wl[(c2 * 2 + cc) * CoutP];
#pragma unroll
                for (int oq = 0; oq < CoutP / 4; oq++) {
                    float4 wv = w4[oq];
                    acc[oq * 4 + 0] += fv[cc] * wv.x;
                    acc[oq * 4 + 1] += fv[cc] * wv.y;
                    acc[oq * 4 + 2] += fv[cc] * wv.z;
                    acc[oq * 4 + 3] += fv[cc] * wv.w;
                }
            }
        }
    } else {
#pragma unroll
        for (int c = 0; c < Cin; c++) {
            float f = row[c];
            const float4* w4 = (const float4*)&wl[c * CoutP];
#pragma unroll
            for (int oq = 0; oq < CoutP / 4; oq++) {
                float4 wv = w4[oq];
                acc[oq * 4 + 0] += f * wv.x;
                acc[oq * 4 + 1] += f * wv.y;
                acc[oq * 4 + 2] += f * wv.z;
                acc[oq * 4 + 3] += f * wv.w;
            }
        }
    }
    float* op = out + (size_t)br * NND * Cout + (size_t)p * Cout;
    if constexpr (Cout % 2 == 0) {
#pragma unroll
        for (int o2 = 0; o2 < Cout / 2; o2++) {
            float2 r;
            r.x = acc[o2 * 2] > 0.f ? acc[o2 * 2] : 0.f;
            r.y = acc[o2 * 2 + 1] > 0.f ? acc[o2 * 2 + 1] : 0.f;
            ((float2*)op)[o2] = r;
        }
    } else {
#pragma unroll
        for (int o = 0; o < Cout; o++) op[o] = acc[o] > 0.f ? acc[o] : 0.f;
    }
}

// ---------------- K6: press conv (3ch,K=3,SAME over 54) + BN2 stats ----------------
__global__ void press_stats_kernel(const float* __restrict__ H2, const float* __restrict__ pw,
                                   const float* __restrict__ pb, float* __restrict__ PRS,
                                   float* __restrict__ st2)
{
    __shared__ float ls[54], lq[54];
    int t = threadIdx.x;
    if (t < 54) { ls[t] = 0.f; lq[t] = 0.f; }
    __syncthreads();
    float pwf[9];
#pragma unroll
    for (int q = 0; q < 9; q++) pwf[q] = pw[q];
    float pbf = pb[0];
    const size_t NM = (size_t)NND * 54;
    size_t base = (size_t)blockIdx.x * 6912;
    for (int q = 0; q < 27; q++) {
        size_t idx = base + q * 256 + t;
        if (idx < NM) {
            int p = (int)(idx / 54), h = (int)(idx % 54);
            float sum = pbf;
#pragma unroll
            for (int i = 0; i < 3; i++)
#pragma unroll
                for (int k = 0; k < 3; k++) {
                    int hh = h + k - 1;
                    if (hh >= 0 && hh < 54)
                        sum += pwf[i * 3 + k] * H2[(size_t)i * NM + (size_t)p * 54 + hh];
                }
            PRS[idx] = sum;
            atomicAdd(&ls[h], sum); atomicAdd(&lq[h], sum * sum);
        }
    }
    __syncthreads();
    if (t < 54) {
        unsafeAtomicAdd(&st2[t], ls[t]);
        unsafeAtomicAdd(&st2[54 + t], lq[t]);
    }
}

// ---------------- K8: emd = affine(pressed) ----------------
__global__ void emd_kernel(float* __restrict__ PRS, const float* __restrict__ sc2,
                           const float* __restrict__ sh2, float* __restrict__ outp)
{
    int id = blockIdx.x * 256 + threadIdx.x;
    if (id >= NND * 54) return;
    int h = id % 54;
    float v = PRS[id] * sc2[h] + sh2[h];
    PRS[id] = v;
    outp[id] = v;
}

// ---------------- K15: graph pooling, block per graph, no atomics ----------------
__global__ void pool_kernel(const float* __restrict__ H1, const float* __restrict__ H2j,
                            const float* __restrict__ H3, const int* __restrict__ gr,
                            float* __restrict__ HG)
{
    __shared__ float part[4][75];
    int t = threadIdx.x;   // 300 = 75 x 4
    int c = t % 75, sub = t / 75;
    int g = blockIdx.x;
    int s = gr[g], e = gr[g + 1];
    float acc = 0.f;
    for (int p = s + sub; p < e; p += 4) {
        float v;
        if (c < 34)      v = H1[(size_t)p * 34 + c];
        else if (c < 59) v = H2j[(size_t)p * 25 + (c - 34)];
        else             v = H3[(size_t)p * 16 + (c - 59)];
        acc += v;
    }
    part[sub][c] = acc;
    __syncthreads();
    if (t < 75) HG[g * 75 + t] = part[0][t] + part[1][t] + part[2][t] + part[3][t];
}

// ---------------- K16: BN3 + cls matmuls, single block ----------------
__global__ void final_kernel(const float* __restrict__ HG, const float* __restrict__ g3,
                             const float* __restrict__ b3,
                             const float* __restrict__ w1, const float* __restrict__ b1,
                             const float* __restrict__ w2, const float* __restrict__ b2,
                             float* __restrict__ outp)
{
    __shared__ float hg[64 * 75];
    __shared__ float o1[64 * 120];
    __shared__ float sc[75], sh[75];
    int t = threadIdx.x;   // 512
    for (int idx = t; idx < 64 * 75; idx += 512) hg[idx] = HG[idx];
    __syncthreads();
    if (t < 75) {
        float s = 0.f, q = 0.f;
        for (int r = 0; r < 64; r++) { float v = hg[r * 75 + t]; s += v; q += v * v; }
        float m = s / 64.f, var = q / 64.f - m * m;
        float rs = rsqrtf(var + EPSV);
        float scale = g3[t] * rs;
        sc[t] = scale; sh[t] = b3[t] - m * scale;
    }
    __syncthreads();
    for (int idx = t; idx < 64 * 75; idx += 512) { int c = idx % 75; hg[idx] = hg[idx] * sc[c] + sh[c]; }
    __syncthreads();
    for (int idx = t; idx < 64 * 120; idx += 512) {
        int r = idx / 120, o = idx % 120;
        float a = b1[o];
        for (int c = 0; c < 75; c++) a += hg[r * 75 + c] * w1[c * 120 + o];
        o1[idx] = a;
    }
    __syncthreads();
    for (int idx = t; idx < 640; idx += 512) {
        int r = idx / 10, o = idx % 10;
        float a = b2[o];
        for (int k = 0; k < 120; k++) a += o1[r * 120 + k] * w2[k * 10 + o];
        outp[idx] = a;
    }
}

extern "C" void kernel_launch(void* const* d_in, const int* in_sizes, int n_in,
                              void* d_out, int out_size, void* d_ws, size_t ws_size,
                              hipStream_t stream)
{
    (void)in_sizes; (void)n_in; (void)out_size;
    const float* nf     = (const float*)d_in[0];
    const float* ew     = (const float*)d_in[1];
    const float* conv_w = (const float*)d_in[2];
    const float* conv_b = (const float*)d_in[3];
    const float* gcn_w  = (const float*)d_in[4];
    const float* gcn_b  = (const float*)d_in[5];
    const float* bn1_g = (const float*)d_in[6],  *bn1_b = (const float*)d_in[7];
    const float* bn2_g = (const float*)d_in[8],  *bn2_b = (const float*)d_in[9];
    const float* bn3_g = (const float*)d_in[10], *bn3_b = (const float*)d_in[11];
    const float* press_w = (const float*)d_in[12], *press_b = (const float*)d_in[13];
    const float* jk_w1 = (const float*)d_in[14], *jk_b1 = (const float*)d_in[15];
    const float* jk_w2 = (const float*)d_in[16], *jk_b2 = (const float*)d_in[17];
    const float* jk_w3 = (const float*)d_in[18], *jk_b3 = (const float*)d_in[19];
    const float* cls1_w = (const float*)d_in[20], *cls1_b = (const float*)d_in[21];
    const float* cls2_w = (const float*)d_in[22], *cls2_b = (const float*)d_in[23];
    const int* esrc = (const int*)d_in[24];
    const int* edst = (const int*)d_in[25];
    const int* gid  = (const int*)d_in[26];
    float* out = (float*)d_out;   // fp32 outputs: (logits[640], emd[2.7M])

    float* ws = (float*)d_ws;
    const size_t NM = (size_t)NND * 96;
    const size_t N54 = (size_t)NND * 54;
    float* X   = ws;                 // 3*NM   (aliased later: AGG)
    float* Y   = X + 3 * NM;         // 3*NM   (nfT during conv; jk buffers later)
    float* H2c = Y + 3 * NM;         // 3*N54
    float* PRS = H2c + 3 * N54;      // N54
    float* ST1 = PRS + N54;          // 576
    float* SC1 = ST1 + 576;          // 288
    float* SH1 = SC1 + 288;          // 288
    float* ST2 = SH1 + 288;          // 108
    float* SC2 = ST2 + 108;          // 54
    float* SH2 = SC2 + 54;           // 54
    float* HG  = SH2 + 54;           // 4800
    // CSR-by-dst + pooling scratch
    int* CNT    = (int*)(HG + 4800);     // 50000
    int* ROWPTR = CNT + NND;             // 50001
    int* CURSOR = ROWPTR + NND + 1;      // 50000
    int* CSRS   = CURSOR + NND;          // 800000
    float* CSRW = (float*)(CSRS + NED);  // 800000
    int* BSUM   = (int*)(CSRW + NED);    // 64 (49 used)
    int* GR     = BSUM + 64;             // 65
    size_t need = (size_t)((float*)(GR + 65) - ws) * sizeof(float);
    if (ws_size < need) return;      // ws too small -> fail loudly in validation

    // aliases
    float* nfT  = Y;                 // [128][NSTR] padded — dead before y_stats writes Y
    float* AGG  = X;
    float* AGG1 = Y;                           // N*54
    float* H1j  = AGG1 + N54;                  // N*34
    float* AGG2 = H1j + (size_t)NND * 34;      // N*34
    float* H2j  = AGG2 + (size_t)NND * 34;     // N*25
    float* AGG3 = H2j + (size_t)NND * 25;      // N*25
    float* H3j  = AGG3 + (size_t)NND * 25;     // N*16

    // zero stats (ST1..SH2 = 1368 floats) and CSR histogram
    hipMemsetAsync(ST1, 0, 1368 * sizeof(float), stream);
    hipMemsetAsync(CNT, 0, NND * sizeof(int), stream);

    // CSR build (multi-block scan) + graph ranges
    hist_kernel<<<(NED + 255) / 256, 256, 0, stream>>>(edst, CNT);
    scanA_kernel<<<49, 256, 0, stream>>>(CNT, BSUM);
    scanB_kernel<<<1, 64, 0, stream>>>(BSUM, ROWPTR, 49);
    scanC_kernel<<<49, 1024, 0, stream>>>(CNT, BSUM, ROWPTR, CURSOR);
    fill_kernel<<<(NED + 255) / 256, 256, 0, stream>>>(esrc, edst, ew, CURSOR, CSRS, CSRW);
    grstart_kernel<<<1, 128, 0, stream>>>(gid, GR);

    // K0: transpose node feats into padded [c][4+p] + zero guard bands
    transpose_kernel<<<dim3((NND + 31) / 32, 4), 256, 0, stream>>>(nf, nfT);
    pad_kernel<<<1, 1024, 0, stream>>>(nfT);

    // K1: dilated convs — 8 nodes/thread as 2 aligned quads, 8 outs/block
    conv_kernel<<<dim3(25, 12, 3), 256, 0, stream>>>(nfT, conv_w, conv_b, X);

    // K2/K3: Y + BN1   (overwrites nfT region — conv already done)
    y_stats_kernel<<<dim3((NND + 63) / 64, 3), 384, 0, stream>>>(X, Y, ST1);
    bn_finalize_kernel<<<1, 512, 0, stream>>>(ST1, bn1_g, bn1_b, SC1, SH1, 288, 96);

    // K4: pull GCN aggregate, 3 branches fused, float4 channels
    pull_bn_kernel<<<(NND * 24 + 255) / 256, 256, 0, stream>>>(
        Y, ROWPTR, CSRS, CSRW, SC1, SH1, AGG);

    // K5: GCN matmul + relu, node-per-thread, 3 branches via gridDim.y
    matmul_node_kernel<96, 54><<<dim3((NND + 127) / 128, 3), 128, 0, stream>>>(
        AGG, gcn_w, gcn_b, H2c);

    // K6/K7/K8: press + BN2 + emd out (fp32 at element offset 640)
    press_stats_kernel<<<(int)((N54 + 6911) / 6912), 256, 0, stream>>>(H2c, press_w, press_b, PRS, ST2);
    bn_finalize_kernel<<<1, 512, 0, stream>>>(ST2, bn2_g, bn2_b, SC2, SH2, 54, 54);
    emd_kernel<<<(int)((N54 + 255) / 256), 256, 0, stream>>>(PRS, SC2, SH2, out + 640);

    // JK layer 1 (Y region dead -> jk buffers)
    pull2_kernel<54><<<(NND * 27 + 255) / 256, 256, 0, stream>>>(PRS, ROWPTR, CSRS, CSRW, AGG1);
    matmul_node_kernel<54, 34><<<dim3((NND + 127) / 128, 1), 128, 0, stream>>>(
        AGG1, jk_w1, jk_b1, H1j);

    // JK layer 2
    pull2_kernel<34><<<(NND * 17 + 255) / 256, 256, 0, stream>>>(H1j, ROWPTR, CSRS, CSRW, AGG2);
    matmul_node_kernel<34, 25><<<dim3((NND + 127) / 128, 1), 128, 0, stream>>>(
        AGG2, jk_w2, jk_b2, H2j);

    // JK layer 3
    pull_kernel<25><<<(NND * 25 + 255) / 256, 256, 0, stream>>>(H2j, ROWPTR, CSRS, CSRW, AGG3);
    matmul_node_kernel<25, 16><<<dim3((NND + 127) / 128, 1), 128, 0, stream>>>(
        AGG3, jk_w3, jk_b3, H3j);

    // pooling (block per graph, no atomics) + final
    pool_kernel<<<NGR, 300, 0, stream>>>(H1j, H2j, H3j, GR, HG);
    final_kernel<<<1, 512, 0, stream>>>(HG, bn3_g, bn3_b, cls1_w, cls1_b, cls2_w, cls2_b, out);
}